// Round 3
// baseline (890.662 us; speedup 1.0000x reference)
//
#include <hip/hip_runtime.h>
#include <cstdint>
#include <cstddef>

#define NN 100000
#define IN_CH 165
#define HID 128
#define NBUCK 782    // ceil(100000 / 128)
#define BCAP 3072    // avg bucket 2048, Poisson sigma ~45 -> 22 sigma margin

typedef __attribute__((ext_vector_type(8))) short short8;
typedef __attribute__((ext_vector_type(4))) float f32x4;

__device__ __forceinline__ ushort f2bf(float v) {
    uint b = __builtin_bit_cast(uint, v);
    return (ushort)((b + 0x7FFFu + ((b >> 16) & 1u)) >> 16);
}
__device__ __forceinline__ float bf2f(ushort u) {
    uint b = ((uint)u) << 16;
    return __builtin_bit_cast(float, b);
}

// ---------------- utility ----------------
__global__ void k_zero_i32(int* __restrict__ p, int n) {
    int i = blockIdx.x * blockDim.x + threadIdx.x;
    if (i < n) p[i] = 0;
}

// ---------------- bucketed CSR build ----------------
// pass 1: append packed (src<<7)|(dst&127) into bucket dst>>7
__global__ void k_bucket(const int* __restrict__ src, const int* __restrict__ dst,
                         int E, int* __restrict__ bcnt, int* __restrict__ bdata) {
    int i = blockIdx.x * blockDim.x + threadIdx.x;
    if (i < E) {
        int d = dst[i];
        int b = d >> 7;
        int p = atomicAdd(&bcnt[b], 1);
        bdata[b * BCAP + p] = (src[i] << 7) | (d & 127);
    }
}

// exclusive scan of bucket counts (NBUCK <= 1024, one workgroup)
__global__ void k_bscan(const int* __restrict__ bcnt, int* __restrict__ bbase) {
    __shared__ int sd[1024];
    int t = threadIdx.x;
    int v = (t < NBUCK) ? bcnt[t] : 0;
    sd[t] = v;
    __syncthreads();
    for (int off = 1; off < 1024; off <<= 1) {
        int x = (t >= off) ? sd[t - off] : 0;
        __syncthreads();
        sd[t] += x;
        __syncthreads();
    }
    if (t < NBUCK) bbase[t] = sd[t] - v;
}

// pass 2: per-bucket local histogram + scan -> row_off, inv, csr fill
__global__ __launch_bounds__(256) void k_csr(
    const int* __restrict__ bcnt, const int* __restrict__ bbase,
    const int* __restrict__ bdata, int* __restrict__ csr,
    int* __restrict__ row_off, float* __restrict__ inv, int N, int E)
{
    __shared__ int hist[128];
    __shared__ int scan[128];
    const int b = blockIdx.x;
    const int t = threadIdx.x;
    const int c = bcnt[b];
    const int base = bbase[b];
    const int* __restrict__ ed = bdata + b * BCAP;

    if (t < 128) hist[t] = 0;
    __syncthreads();
    for (int i = t; i < c; i += 256) atomicAdd(&hist[ed[i] & 127], 1);
    __syncthreads();
    if (t < 128) scan[t] = hist[t];
    __syncthreads();
    for (int off = 1; off < 128; off <<= 1) {
        int x = 0;
        if (t < 128 && t >= off) x = scan[t - off];
        __syncthreads();
        if (t < 128) scan[t] += x;
        __syncthreads();
    }
    if (t < 128) {
        const int node = b * 128 + t;
        const int excl = scan[t] - hist[t];
        if (node < N) {
            row_off[node] = base + excl;
            inv[node] = 1.0f / (float)max(hist[t], 1);
        }
        hist[t] = excl;  // becomes running local position
    }
    if (b == 0 && t == 0) row_off[N] = E;
    __syncthreads();
    for (int i = t; i < c; i += 256) {
        const int e = ed[i];
        const int p = atomicAdd(&hist[e & 127], 1);
        csr[base + p] = e >> 7;
    }
}

// ---------------- weight pack: W[j][k] (row-major [128][K]) -> k-blocked bf16 hi/lo
// out[(k>>3)*1024 + j*8 + (k&7)], zero-padded to KP
__global__ void k_wpack(const float* __restrict__ W, int K, int KP,
                        ushort* __restrict__ Wh, ushort* __restrict__ Wl) {
    int idx = blockIdx.x * blockDim.x + threadIdx.x;
    if (idx >= KP * HID) return;
    int k = idx / HID;
    int j = idx - k * HID;
    float v = (k < K) ? W[j * K + k] : 0.0f;
    ushort h = f2bf(v);
    ushort l = f2bf(v - bf2f(h));
    int o = (k >> 3) * (HID * 8) + j * 8 + (k & 7);
    Wh[o] = h;
    Wl[o] = l;
}

// ---------------- MFMA dual GEMM (bf16x3 split fp32): yl = h @ Wl^T, yr = h @ Wr^T
// 32 nodes/block, 256 threads (4 waves). Wave w: mat = w&1, col-blocks (w>>1)*4 .. +3.
// A staged in LDS as bf16 hi/lo, row-major with XOR swizzle byte ^= (row&7)<<4.
template <int K, int KP>
__global__ __launch_bounds__(256) void k_gemm_mfma(
    const float* __restrict__ h,
    const ushort* __restrict__ Wlh, const ushort* __restrict__ Wll,
    const ushort* __restrict__ Wrh, const ushort* __restrict__ Wrl,
    float* __restrict__ yl, float* __restrict__ yr)
{
    constexpr int RS = KP * 2;  // LDS row stride (bytes)
    __shared__ __align__(16) char Ah[32 * RS];
    __shared__ __align__(16) char Al[32 * RS];
    const int tid = threadIdx.x;
    const int node0 = blockIdx.x * 32;
    const float* __restrict__ hp = h + (size_t)node0 * K;

    // ---- stage + split-convert 32 x K tile ----
    constexpr int Q = 32 * (KP / 4);
    for (int q = tid; q < Q; q += 256) {
        const int r = q / (KP / 4);
        const int kp = (q - r * (KP / 4)) * 4;
        float v0, v1, v2, v3;
        if constexpr (K % 4 == 0) {
            const float4 v = *reinterpret_cast<const float4*>(&hp[r * K + kp]);
            v0 = v.x; v1 = v.y; v2 = v.z; v3 = v.w;
        } else {
            v0 = (kp + 0 < K) ? hp[r * K + kp + 0] : 0.0f;
            v1 = (kp + 1 < K) ? hp[r * K + kp + 1] : 0.0f;
            v2 = (kp + 2 < K) ? hp[r * K + kp + 2] : 0.0f;
            v3 = (kp + 3 < K) ? hp[r * K + kp + 3] : 0.0f;
        }
        const ushort h0 = f2bf(v0), h1 = f2bf(v1), h2 = f2bf(v2), h3 = f2bf(v3);
        const ushort l0 = f2bf(v0 - bf2f(h0)), l1 = f2bf(v1 - bf2f(h1));
        const ushort l2 = f2bf(v2 - bf2f(h2)), l3 = f2bf(v3 - bf2f(h3));
        const int byte = r * RS + ((kp * 2) ^ ((r & 7) << 4));
        *reinterpret_cast<ushort4*>(Ah + byte) = make_ushort4(h0, h1, h2, h3);
        *reinterpret_cast<ushort4*>(Al + byte) = make_ushort4(l0, l1, l2, l3);
    }
    __syncthreads();

    // ---- MFMA phase ----
    const int lane = tid & 63;
    const int w = tid >> 6;
    const int trow = lane & 15;   // A row within tile / D col within tile
    const int kg = lane >> 4;     // k-group
    const ushort* __restrict__ Bh = (w & 1) ? Wrh : Wlh;
    const ushort* __restrict__ Bl = (w & 1) ? Wrl : Wll;
    float* __restrict__ yo = (w & 1) ? yr : yl;
    const int cb0 = (w >> 1) * 4;

    f32x4 acc[2][4];
#pragma unroll
    for (int a = 0; a < 2; ++a)
#pragma unroll
        for (int b = 0; b < 4; ++b) acc[a][b] = (f32x4){0.f, 0.f, 0.f, 0.f};

    const int xo = (trow & 7) << 4;
    const char* __restrict__ pA0 = Ah + trow * RS;
    const char* __restrict__ pA1 = Ah + (trow + 16) * RS;
    const char* __restrict__ pL0 = Al + trow * RS;
    const char* __restrict__ pL1 = Al + (trow + 16) * RS;

    constexpr int KS = KP / 32;
    for (int ks = 0; ks < KS; ++ks) {
        const int kbyte = (ks * 64 + kg * 16) ^ xo;
        const short8 a0h = *reinterpret_cast<const short8*>(pA0 + kbyte);
        const short8 a0l = *reinterpret_cast<const short8*>(pL0 + kbyte);
        const short8 a1h = *reinterpret_cast<const short8*>(pA1 + kbyte);
        const short8 a1l = *reinterpret_cast<const short8*>(pL1 + kbyte);
        const int bbase = (ks * 4 + kg) * (HID * 8) + trow * 8;
#pragma unroll
        for (int ci = 0; ci < 4; ++ci) {
            const int bo = bbase + (cb0 + ci) * 128;
            const short8 bh = *reinterpret_cast<const short8*>(Bh + bo);
            const short8 bl = *reinterpret_cast<const short8*>(Bl + bo);
            acc[0][ci] = __builtin_amdgcn_mfma_f32_16x16x32_bf16(a0l, bh, acc[0][ci], 0, 0, 0);
            acc[0][ci] = __builtin_amdgcn_mfma_f32_16x16x32_bf16(a0h, bl, acc[0][ci], 0, 0, 0);
            acc[0][ci] = __builtin_amdgcn_mfma_f32_16x16x32_bf16(a0h, bh, acc[0][ci], 0, 0, 0);
            acc[1][ci] = __builtin_amdgcn_mfma_f32_16x16x32_bf16(a1l, bh, acc[1][ci], 0, 0, 0);
            acc[1][ci] = __builtin_amdgcn_mfma_f32_16x16x32_bf16(a1h, bl, acc[1][ci], 0, 0, 0);
            acc[1][ci] = __builtin_amdgcn_mfma_f32_16x16x32_bf16(a1h, bh, acc[1][ci], 0, 0, 0);
        }
    }

    // ---- epilogue: D col = lane&15, row = (lane>>4)*4 + reg ----
#pragma unroll
    for (int rb = 0; rb < 2; ++rb) {
        const int nb_ = node0 + rb * 16 + kg * 4;
#pragma unroll
        for (int ci = 0; ci < 4; ++ci) {
            const int col = (cb0 + ci) * 16 + trow;
            const f32x4 a = acc[rb][ci];
#pragma unroll
            for (int rr = 0; rr < 4; ++rr)
                yo[(size_t)(nb_ + rr) * HID + col] = a[rr];
        }
    }
}

// ---------------- aggregate + combine; wave per node, float2 per lane ----------------
// HEAD=0: h_next = relu(sum*inv + bias + yr)  (written to outp as [N][128])
// HEAD=1: v = sum*inv + bias + yr; out[n][c] = sum_j v_j * Wout[c][j] + bout[c]
template <int HEAD>
__global__ __launch_bounds__(256) void k_agg2(
    const float* __restrict__ yl, const int* __restrict__ row_off,
    const int* __restrict__ csr, const float* __restrict__ inv,
    const float* __restrict__ bias, const float* __restrict__ yr,
    float* __restrict__ outp, const float* __restrict__ Wout,
    const float* __restrict__ bout, int N)
{
    const int wid = (blockIdx.x * 256 + (int)threadIdx.x) >> 6;
    const int lane = threadIdx.x & 63;
    if (wid >= N) return;
    const int beg = row_off[wid];
    const int end = row_off[wid + 1];
    const float2* __restrict__ Y = (const float2*)yl;
    float ax0 = 0.f, ay0 = 0.f, ax1 = 0.f, ay1 = 0.f;
    float ax2 = 0.f, ay2 = 0.f, ax3 = 0.f, ay3 = 0.f;
    int e = beg;
    for (; e + 4 <= end; e += 4) {
        const int s0 = csr[e + 0], s1 = csr[e + 1], s2 = csr[e + 2], s3 = csr[e + 3];
        const float2 v0 = Y[(size_t)s0 * 64 + lane];
        const float2 v1 = Y[(size_t)s1 * 64 + lane];
        const float2 v2 = Y[(size_t)s2 * 64 + lane];
        const float2 v3 = Y[(size_t)s3 * 64 + lane];
        ax0 += v0.x; ay0 += v0.y;
        ax1 += v1.x; ay1 += v1.y;
        ax2 += v2.x; ay2 += v2.y;
        ax3 += v3.x; ay3 += v3.y;
    }
    for (; e < end; ++e) {
        const float2 v = Y[(size_t)csr[e] * 64 + lane];
        ax0 += v.x; ay0 += v.y;
    }
    const float iv = inv[wid];
    const float2 r = ((const float2*)yr)[(size_t)wid * 64 + lane];
    const float2 b = ((const float2*)bias)[lane];
    float vx = (ax0 + ax1 + ax2 + ax3) * iv + b.x + r.x;
    float vy = (ay0 + ay1 + ay2 + ay3) * iv + b.y + r.y;
    if constexpr (!HEAD) {
        vx = fmaxf(vx, 0.0f);
        vy = fmaxf(vy, 0.0f);
        ((float2*)outp)[(size_t)wid * 64 + lane] = make_float2(vx, vy);
    } else {
        float p0 = vx * Wout[2 * lane] + vy * Wout[2 * lane + 1];
        float p1 = vx * Wout[128 + 2 * lane] + vy * Wout[129 + 2 * lane];
#pragma unroll
        for (int off = 32; off > 0; off >>= 1) {
            p0 += __shfl_xor(p0, off);
            p1 += __shfl_xor(p1, off);
        }
        if (lane == 0) {
            outp[(size_t)wid * 2 + 0] = p0 + bout[0];
            outp[(size_t)wid * 2 + 1] = p1 + bout[1];
        }
    }
}

extern "C" void kernel_launch(void* const* d_in, const int* in_sizes, int n_in,
                              void* d_out, int out_size, void* d_ws, size_t ws_size,
                              hipStream_t stream) {
    const float* x    = (const float*)d_in[0];
    const int*   ei   = (const int*)d_in[1];
    const float* Wl0  = (const float*)d_in[2];
    const float* bl0  = (const float*)d_in[3];
    const float* Wr0  = (const float*)d_in[4];
    const float* Wl1  = (const float*)d_in[5];
    const float* bl1  = (const float*)d_in[6];
    const float* Wr1  = (const float*)d_in[7];
    const float* Wl2  = (const float*)d_in[8];
    const float* bl2  = (const float*)d_in[9];
    const float* Wr2  = (const float*)d_in[10];
    const float* Wout = (const float*)d_in[11];
    const float* bout = (const float*)d_in[12];

    const int N = NN;
    const int E = in_sizes[1] / 2;
    const int* src = ei;
    const int* dst = ei + E;

    // workspace carve-up (256B aligned)
    char* w = (char*)d_ws;
    auto alloc = [&](size_t bytes) {
        char* p = w;
        w += (bytes + 255) & ~(size_t)255;
        return p;
    };
    int*    bcnt    = (int*)alloc((size_t)(NBUCK + 8) * 4);
    int*    bbase   = (int*)alloc((size_t)(NBUCK + 8) * 4);
    int*    bdata   = (int*)alloc((size_t)NBUCK * BCAP * 4);
    int*    row_off = (int*)alloc((size_t)(N + 1) * 4);
    float*  inv     = (float*)alloc((size_t)N * 4);
    int*    csr     = (int*)alloc((size_t)E * 4);
    ushort* Wl0h    = (ushort*)alloc((size_t)192 * HID * 2);
    ushort* Wl0l    = (ushort*)alloc((size_t)192 * HID * 2);
    ushort* Wr0h    = (ushort*)alloc((size_t)192 * HID * 2);
    ushort* Wr0l    = (ushort*)alloc((size_t)192 * HID * 2);
    ushort* Wl1h    = (ushort*)alloc((size_t)HID * HID * 2);
    ushort* Wl1l    = (ushort*)alloc((size_t)HID * HID * 2);
    ushort* Wr1h    = (ushort*)alloc((size_t)HID * HID * 2);
    ushort* Wr1l    = (ushort*)alloc((size_t)HID * HID * 2);
    ushort* Wl2h    = (ushort*)alloc((size_t)HID * HID * 2);
    ushort* Wl2l    = (ushort*)alloc((size_t)HID * HID * 2);
    ushort* Wr2h    = (ushort*)alloc((size_t)HID * HID * 2);
    ushort* Wr2l    = (ushort*)alloc((size_t)HID * HID * 2);
    float*  B0      = (float*)alloc((size_t)N * HID * 4);
    float*  B1      = (float*)alloc((size_t)N * HID * 4);
    float*  B2      = (float*)alloc((size_t)N * HID * 4);

    // ---- bucketed CSR build ----
    k_zero_i32<<<(NBUCK + 8 + 255) / 256, 256, 0, stream>>>(bcnt, NBUCK + 8);
    k_bucket<<<(E + 255) / 256, 256, 0, stream>>>(src, dst, E, bcnt, bdata);
    k_bscan<<<1, 1024, 0, stream>>>(bcnt, bbase);
    k_csr<<<NBUCK, 256, 0, stream>>>(bcnt, bbase, bdata, csr, row_off, inv, N, E);

    // ---- weight packing (bf16 hi/lo, k-blocked) ----
    k_wpack<<<(192 * HID + 255) / 256, 256, 0, stream>>>(Wl0, IN_CH, 192, Wl0h, Wl0l);
    k_wpack<<<(192 * HID + 255) / 256, 256, 0, stream>>>(Wr0, IN_CH, 192, Wr0h, Wr0l);
    k_wpack<<<(HID * HID + 255) / 256, 256, 0, stream>>>(Wl1, HID, HID, Wl1h, Wl1l);
    k_wpack<<<(HID * HID + 255) / 256, 256, 0, stream>>>(Wr1, HID, HID, Wr1h, Wr1l);
    k_wpack<<<(HID * HID + 255) / 256, 256, 0, stream>>>(Wl2, HID, HID, Wl2h, Wl2l);
    k_wpack<<<(HID * HID + 255) / 256, 256, 0, stream>>>(Wr2, HID, HID, Wr2h, Wr2l);

    const int gemm_grid = N / 32;   // 3125
    const int agg_grid = N / 4;     // 25000

    // ---- layer 0: h = x (K=165, pad 192) ----
    k_gemm_mfma<IN_CH, 192><<<gemm_grid, 256, 0, stream>>>(x, Wl0h, Wl0l, Wr0h, Wr0l, B0, B1);
    k_agg2<0><<<agg_grid, 256, 0, stream>>>(B0, row_off, csr, inv, bl0, B1, B1, nullptr, nullptr, N);

    // ---- layer 1 ----
    k_gemm_mfma<HID, HID><<<gemm_grid, 256, 0, stream>>>(B1, Wl1h, Wl1l, Wr1h, Wr1l, B0, B2);
    k_agg2<0><<<agg_grid, 256, 0, stream>>>(B0, row_off, csr, inv, bl1, B2, B2, nullptr, nullptr, N);

    // ---- layer 2 + fused output head ----
    k_gemm_mfma<HID, HID><<<gemm_grid, 256, 0, stream>>>(B2, Wl2h, Wl2l, Wr2h, Wr2l, B0, B1);
    k_agg2<1><<<agg_grid, 256, 0, stream>>>(B0, row_off, csr, inv, bl2, B1, (float*)d_out, Wout, bout, N);
}

// Round 4
// 590.614 us; speedup vs baseline: 1.5080x; 1.5080x over previous
//
#include <hip/hip_runtime.h>
#include <cstdint>
#include <cstddef>

#define NN 100000
#define IN_CH 165
#define HID 128

#define NBUCK 196     // ceil(100000/512) buckets of 512 nodes (dst>>9)
#define NPB 512
#define BMAX 10240    // max edges/bucket (mean 8163, +23 sigma)
#define NWG 64        // scatter workgroups

typedef __attribute__((ext_vector_type(8))) short short8;
typedef __attribute__((ext_vector_type(4))) float f32x4;

__device__ __forceinline__ ushort f2bf(float v) {
    uint b = __builtin_bit_cast(uint, v);
    return (ushort)((b + 0x7FFFu + ((b >> 16) & 1u)) >> 16);
}
__device__ __forceinline__ float bf2f(ushort u) {
    uint b = ((uint)u) << 16;
    return __builtin_bit_cast(float, b);
}

// ================= CSR build: 4-phase bucket sort, all stores coalesced =================
// phase 1: per-WG histogram over NBUCK buckets
__global__ __launch_bounds__(256) void k_cnt(const int* __restrict__ dst, int E, int chunk,
                                             int* __restrict__ cnt) {
    __shared__ int h[NBUCK];
    const int w = blockIdx.x, t = threadIdx.x;
    for (int b = t; b < NBUCK; b += 256) h[b] = 0;
    __syncthreads();
    const int beg = w * chunk, end = min(E, beg + chunk);
    for (int i = beg + t; i < end; i += 256) atomicAdd(&h[dst[i] >> 9], 1);
    __syncthreads();
    for (int b = t; b < NBUCK; b += 256) cnt[w * NBUCK + b] = h[b];
}

// phase 2: exclusive scan of the 64x196 count matrix in (b-major, w-minor) order.
// gaddr[b*64+w] = start of (w,b) segment; bucket b region = [gaddr[b*64], gaddr[(b+1)*64])
__global__ __launch_bounds__(256) void k_cscan(const int* __restrict__ cnt,
                                               int* __restrict__ gaddr) {
    __shared__ int ps[256];
    const int t = threadIdx.x;           // 12544 = 256 * 49
    int s = 0;
    for (int k = 0; k < 49; k++) {
        const int m = t * 49 + k;
        s += cnt[(m & 63) * NBUCK + (m >> 6)];
    }
    ps[t] = s;
    __syncthreads();
    for (int off = 1; off < 256; off <<= 1) {
        int v = (t >= off) ? ps[t - off] : 0;
        __syncthreads();
        ps[t] += v;
        __syncthreads();
    }
    int run = (t > 0) ? ps[t - 1] : 0;
    for (int k = 0; k < 49; k++) {
        const int m = t * 49 + k;
        gaddr[m] = run;
        run += cnt[(m & 63) * NBUCK + (m >> 6)];
    }
}

// phase 3: tile-staged scatter of packed keys (src<<9)|(dst&511) into bucket-contiguous bdata
__global__ __launch_bounds__(256) void k_scatter(const int* __restrict__ src,
                                                 const int* __restrict__ dst, int E, int chunk,
                                                 const int* __restrict__ gaddr,
                                                 int* __restrict__ bdata) {
    __shared__ int cur[NBUCK];
    __shared__ int thist[256];
    __shared__ int sA[256];
    __shared__ int tex[NBUCK];
    __shared__ int lpos[NBUCK];
    __shared__ int staged[2048];
    __shared__ int addrs[2048];
    const int w = blockIdx.x, t = threadIdx.x;
    for (int b = t; b < NBUCK; b += 256) cur[b] = gaddr[b * NWG + w];
    const int beg = w * chunk, end = min(E, beg + chunk);
    for (int tb = beg; tb < end; tb += 2048) {
        const int tcnt = min(2048, end - tb);
        int key[8], bk[8];
#pragma unroll
        for (int j = 0; j < 8; j++) {
            const int i = tb + j * 256 + t;
            if (i < end) {
                const int d = dst[i];
                bk[j] = d >> 9;
                key[j] = (src[i] << 9) | (d & 511);
            } else bk[j] = -1;
        }
        __syncthreads();
        thist[t] = 0;
        __syncthreads();
#pragma unroll
        for (int j = 0; j < 8; j++)
            if (bk[j] >= 0) atomicAdd(&thist[bk[j]], 1);
        __syncthreads();
        sA[t] = thist[t];
        __syncthreads();
        for (int off = 1; off < 256; off <<= 1) {
            int v = (t >= off) ? sA[t - off] : 0;
            __syncthreads();
            sA[t] += v;
            __syncthreads();
        }
        if (t < NBUCK) {
            const int e = sA[t] - thist[t];
            tex[t] = e;
            lpos[t] = e;
        }
        __syncthreads();
#pragma unroll
        for (int j = 0; j < 8; j++)
            if (bk[j] >= 0) {
                const int b = bk[j];
                const int l = atomicAdd(&lpos[b], 1);
                staged[l] = key[j];
                addrs[l] = cur[b] + (l - tex[b]);
            }
        __syncthreads();
        for (int l = t; l < tcnt; l += 256) bdata[addrs[l]] = staged[l];
        __syncthreads();
        if (t < NBUCK) cur[t] += thist[t];
    }
}

// phase 4: per-bucket LDS counting sort -> csr (coalesced), row_off, inv
__global__ __launch_bounds__(256) void k_csr2(const int* __restrict__ gaddr,
                                              const int* __restrict__ bdata, int E,
                                              int* __restrict__ csr, int* __restrict__ row_off,
                                              float* __restrict__ inv, int N) {
    __shared__ int keys[BMAX];
    __shared__ int sorted[BMAX];
    __shared__ int h5[NPB];
    __shared__ int s5[NPB];
    const int b = blockIdx.x, t = threadIdx.x;
    const int base = gaddr[b * NWG];
    const int nxt = (b == NBUCK - 1) ? E : gaddr[(b + 1) * NWG];
    const int tot = min(nxt - base, BMAX);
    for (int i = t; i < tot; i += 256) keys[i] = bdata[base + i];
    h5[t] = 0;
    h5[t + 256] = 0;
    __syncthreads();
    for (int i = t; i < tot; i += 256) atomicAdd(&h5[keys[i] & 511], 1);
    __syncthreads();
    s5[t] = h5[t];
    s5[t + 256] = h5[t + 256];
    __syncthreads();
    for (int off = 1; off < 512; off <<= 1) {
        const int a = (t >= off) ? s5[t - off] : 0;
        const int c = (t + 256 >= off) ? s5[t + 256 - off] : 0;
        __syncthreads();
        s5[t] += a;
        s5[t + 256] += c;
        __syncthreads();
    }
    const int e0 = s5[t] - h5[t];
    const int e1 = s5[t + 256] - h5[t + 256];
    __syncthreads();
    s5[t] = e0;
    s5[t + 256] = e1;
    const int n0 = b * NPB + t, n1 = b * NPB + t + 256;
    if (n0 < N) { row_off[n0] = base + e0; inv[n0] = 1.0f / (float)max(h5[t], 1); }
    if (n1 < N) { row_off[n1] = base + e1; inv[n1] = 1.0f / (float)max(h5[t + 256], 1); }
    if (b == 0 && t == 0) row_off[N] = E;
    __syncthreads();
    for (int i = t; i < tot; i += 256) {
        const int k = keys[i];
        const int p = atomicAdd(&s5[k & 511], 1);
        sorted[p] = k;
    }
    __syncthreads();
    for (int i = t; i < tot; i += 256) csr[base + i] = sorted[i] >> 9;
}

// ================= weight pack (all 6 matrices in one launch) =================
// layout: out[(k>>3)*1024 + j*8 + (k&7)], zero-padded to KP
__device__ __forceinline__ void wpack_one(const float* __restrict__ W, int K, int idx,
                                          ushort* __restrict__ Wh, ushort* __restrict__ Wl) {
    const int k = idx >> 7;
    const int j = idx & 127;
    const float v = (k < K) ? W[j * K + k] : 0.0f;
    const ushort h = f2bf(v);
    const ushort l = f2bf(v - bf2f(h));
    const int o = (k >> 3) * (HID * 8) + j * 8 + (k & 7);
    Wh[o] = h;
    Wl[o] = l;
}

__global__ void k_wpack_all(const float* __restrict__ Wl0, const float* __restrict__ Wr0,
                            const float* __restrict__ Wl1, const float* __restrict__ Wr1,
                            const float* __restrict__ Wl2, const float* __restrict__ Wr2,
                            ushort* __restrict__ Wl0h, ushort* __restrict__ Wl0l,
                            ushort* __restrict__ Wr0h, ushort* __restrict__ Wr0l,
                            ushort* __restrict__ Wl1h, ushort* __restrict__ Wl1l,
                            ushort* __restrict__ Wr1h, ushort* __restrict__ Wr1l,
                            ushort* __restrict__ Wl2h, ushort* __restrict__ Wl2l,
                            ushort* __restrict__ Wr2h, ushort* __restrict__ Wr2l) {
    const int gid = blockIdx.x * blockDim.x + threadIdx.x;
    if (gid < 192 * HID) {
        wpack_one(Wl0, IN_CH, gid, Wl0h, Wl0l);
        wpack_one(Wr0, IN_CH, gid, Wr0h, Wr0l);
    }
    if (gid < 128 * HID) {
        wpack_one(Wl1, HID, gid, Wl1h, Wl1l);
        wpack_one(Wr1, HID, gid, Wr1h, Wr1l);
        wpack_one(Wl2, HID, gid, Wl2h, Wl2l);
        wpack_one(Wr2, HID, gid, Wr2h, Wr2l);
    }
}

// ================= MFMA dual GEMM (bf16x3 split fp32) =================
template <int K, int KP>
__global__ __launch_bounds__(256) void k_gemm_mfma(
    const float* __restrict__ h,
    const ushort* __restrict__ Wlh, const ushort* __restrict__ Wll,
    const ushort* __restrict__ Wrh, const ushort* __restrict__ Wrl,
    float* __restrict__ yl, float* __restrict__ yr)
{
    constexpr int RS = KP * 2;  // LDS row stride (bytes)
    __shared__ __align__(16) char Ah[32 * RS];
    __shared__ __align__(16) char Al[32 * RS];
    const int tid = threadIdx.x;
    const int node0 = blockIdx.x * 32;
    const float* __restrict__ hp = h + (size_t)node0 * K;

    constexpr int Q = 32 * (KP / 4);
    for (int q = tid; q < Q; q += 256) {
        const int r = q / (KP / 4);
        const int kp = (q - r * (KP / 4)) * 4;
        float v0, v1, v2, v3;
        if constexpr (K % 4 == 0) {
            const float4 v = *reinterpret_cast<const float4*>(&hp[r * K + kp]);
            v0 = v.x; v1 = v.y; v2 = v.z; v3 = v.w;
        } else {
            v0 = (kp + 0 < K) ? hp[r * K + kp + 0] : 0.0f;
            v1 = (kp + 1 < K) ? hp[r * K + kp + 1] : 0.0f;
            v2 = (kp + 2 < K) ? hp[r * K + kp + 2] : 0.0f;
            v3 = (kp + 3 < K) ? hp[r * K + kp + 3] : 0.0f;
        }
        const ushort h0 = f2bf(v0), h1 = f2bf(v1), h2 = f2bf(v2), h3 = f2bf(v3);
        const ushort l0 = f2bf(v0 - bf2f(h0)), l1 = f2bf(v1 - bf2f(h1));
        const ushort l2 = f2bf(v2 - bf2f(h2)), l3 = f2bf(v3 - bf2f(h3));
        const int byte = r * RS + ((kp * 2) ^ ((r & 7) << 4));
        *reinterpret_cast<ushort4*>(Ah + byte) = make_ushort4(h0, h1, h2, h3);
        *reinterpret_cast<ushort4*>(Al + byte) = make_ushort4(l0, l1, l2, l3);
    }
    __syncthreads();

    const int lane = tid & 63;
    const int w = tid >> 6;
    const int trow = lane & 15;
    const int kg = lane >> 4;
    const ushort* __restrict__ Bh = (w & 1) ? Wrh : Wlh;
    const ushort* __restrict__ Bl = (w & 1) ? Wrl : Wll;
    float* __restrict__ yo = (w & 1) ? yr : yl;
    const int cb0 = (w >> 1) * 4;

    f32x4 acc[2][4];
#pragma unroll
    for (int a = 0; a < 2; ++a)
#pragma unroll
        for (int b = 0; b < 4; ++b) acc[a][b] = (f32x4){0.f, 0.f, 0.f, 0.f};

    const int xo = (trow & 7) << 4;
    const char* __restrict__ pA0 = Ah + trow * RS;
    const char* __restrict__ pA1 = Ah + (trow + 16) * RS;
    const char* __restrict__ pL0 = Al + trow * RS;
    const char* __restrict__ pL1 = Al + (trow + 16) * RS;

    constexpr int KS = KP / 32;
    for (int ks = 0; ks < KS; ++ks) {
        const int kbyte = (ks * 64 + kg * 16) ^ xo;
        const short8 a0h = *reinterpret_cast<const short8*>(pA0 + kbyte);
        const short8 a0l = *reinterpret_cast<const short8*>(pL0 + kbyte);
        const short8 a1h = *reinterpret_cast<const short8*>(pA1 + kbyte);
        const short8 a1l = *reinterpret_cast<const short8*>(pL1 + kbyte);
        const int bbase = (ks * 4 + kg) * (HID * 8) + trow * 8;
#pragma unroll
        for (int ci = 0; ci < 4; ++ci) {
            const int bo = bbase + (cb0 + ci) * 128;
            const short8 bh = *reinterpret_cast<const short8*>(Bh + bo);
            const short8 bl = *reinterpret_cast<const short8*>(Bl + bo);
            acc[0][ci] = __builtin_amdgcn_mfma_f32_16x16x32_bf16(a0l, bh, acc[0][ci], 0, 0, 0);
            acc[0][ci] = __builtin_amdgcn_mfma_f32_16x16x32_bf16(a0h, bl, acc[0][ci], 0, 0, 0);
            acc[0][ci] = __builtin_amdgcn_mfma_f32_16x16x32_bf16(a0h, bh, acc[0][ci], 0, 0, 0);
            acc[1][ci] = __builtin_amdgcn_mfma_f32_16x16x32_bf16(a1l, bh, acc[1][ci], 0, 0, 0);
            acc[1][ci] = __builtin_amdgcn_mfma_f32_16x16x32_bf16(a1h, bl, acc[1][ci], 0, 0, 0);
            acc[1][ci] = __builtin_amdgcn_mfma_f32_16x16x32_bf16(a1h, bh, acc[1][ci], 0, 0, 0);
        }
    }

#pragma unroll
    for (int rb = 0; rb < 2; ++rb) {
        const int nb_ = node0 + rb * 16 + kg * 4;
#pragma unroll
        for (int ci = 0; ci < 4; ++ci) {
            const int col = (cb0 + ci) * 16 + trow;
            const f32x4 a = acc[rb][ci];
#pragma unroll
            for (int rr = 0; rr < 4; ++rr)
                yo[(size_t)(nb_ + rr) * HID + col] = a[rr];
        }
    }
}

// ================= aggregate + combine; wave per node =================
template <int HEAD>
__global__ __launch_bounds__(256) void k_agg2(
    const float* __restrict__ yl, const int* __restrict__ row_off,
    const int* __restrict__ csr, const float* __restrict__ inv,
    const float* __restrict__ bias, const float* __restrict__ yr,
    float* __restrict__ outp, const float* __restrict__ Wout,
    const float* __restrict__ bout, int N)
{
    const int wid = (blockIdx.x * 256 + (int)threadIdx.x) >> 6;
    const int lane = threadIdx.x & 63;
    if (wid >= N) return;
    const int beg = row_off[wid];
    const int end = row_off[wid + 1];
    const float2* __restrict__ Y = (const float2*)yl;
    float ax0 = 0.f, ay0 = 0.f, ax1 = 0.f, ay1 = 0.f;
    float ax2 = 0.f, ay2 = 0.f, ax3 = 0.f, ay3 = 0.f;
    int e = beg;
    for (; e + 4 <= end; e += 4) {
        const int s0 = csr[e + 0], s1 = csr[e + 1], s2 = csr[e + 2], s3 = csr[e + 3];
        const float2 v0 = Y[(size_t)s0 * 64 + lane];
        const float2 v1 = Y[(size_t)s1 * 64 + lane];
        const float2 v2 = Y[(size_t)s2 * 64 + lane];
        const float2 v3 = Y[(size_t)s3 * 64 + lane];
        ax0 += v0.x; ay0 += v0.y;
        ax1 += v1.x; ay1 += v1.y;
        ax2 += v2.x; ay2 += v2.y;
        ax3 += v3.x; ay3 += v3.y;
    }
    for (; e < end; ++e) {
        const float2 v = Y[(size_t)csr[e] * 64 + lane];
        ax0 += v.x; ay0 += v.y;
    }
    const float iv = inv[wid];
    const float2 r = ((const float2*)yr)[(size_t)wid * 64 + lane];
    const float2 b = ((const float2*)bias)[lane];
    float vx = (ax0 + ax1 + ax2 + ax3) * iv + b.x + r.x;
    float vy = (ay0 + ay1 + ay2 + ay3) * iv + b.y + r.y;
    if constexpr (!HEAD) {
        vx = fmaxf(vx, 0.0f);
        vy = fmaxf(vy, 0.0f);
        ((float2*)outp)[(size_t)wid * 64 + lane] = make_float2(vx, vy);
    } else {
        float p0 = vx * Wout[2 * lane] + vy * Wout[2 * lane + 1];
        float p1 = vx * Wout[128 + 2 * lane] + vy * Wout[129 + 2 * lane];
#pragma unroll
        for (int off = 32; off > 0; off >>= 1) {
            p0 += __shfl_xor(p0, off);
            p1 += __shfl_xor(p1, off);
        }
        if (lane == 0) {
            outp[(size_t)wid * 2 + 0] = p0 + bout[0];
            outp[(size_t)wid * 2 + 1] = p1 + bout[1];
        }
    }
}

extern "C" void kernel_launch(void* const* d_in, const int* in_sizes, int n_in,
                              void* d_out, int out_size, void* d_ws, size_t ws_size,
                              hipStream_t stream) {
    const float* x    = (const float*)d_in[0];
    const int*   ei   = (const int*)d_in[1];
    const float* Wl0  = (const float*)d_in[2];
    const float* bl0  = (const float*)d_in[3];
    const float* Wr0  = (const float*)d_in[4];
    const float* Wl1  = (const float*)d_in[5];
    const float* bl1  = (const float*)d_in[6];
    const float* Wr1  = (const float*)d_in[7];
    const float* Wl2  = (const float*)d_in[8];
    const float* bl2  = (const float*)d_in[9];
    const float* Wr2  = (const float*)d_in[10];
    const float* Wout = (const float*)d_in[11];
    const float* bout = (const float*)d_in[12];

    const int N = NN;
    const int E = in_sizes[1] / 2;
    const int* src = ei;
    const int* dst = ei + E;
    const int chunk = (E + NWG - 1) / NWG;

    // workspace carve-up (256B aligned)
    char* w = (char*)d_ws;
    auto alloc = [&](size_t bytes) {
        char* p = w;
        w += (bytes + 255) & ~(size_t)255;
        return p;
    };
    int*    cnt     = (int*)alloc((size_t)NWG * NBUCK * 4);
    int*    gaddr   = (int*)alloc((size_t)NWG * NBUCK * 4);
    int*    bdata   = (int*)alloc((size_t)E * 4);
    int*    row_off = (int*)alloc((size_t)(N + 1) * 4);
    float*  inv     = (float*)alloc((size_t)N * 4);
    int*    csr     = (int*)alloc((size_t)E * 4);
    ushort* Wl0h    = (ushort*)alloc((size_t)192 * HID * 2);
    ushort* Wl0l    = (ushort*)alloc((size_t)192 * HID * 2);
    ushort* Wr0h    = (ushort*)alloc((size_t)192 * HID * 2);
    ushort* Wr0l    = (ushort*)alloc((size_t)192 * HID * 2);
    ushort* Wl1h    = (ushort*)alloc((size_t)HID * HID * 2);
    ushort* Wl1l    = (ushort*)alloc((size_t)HID * HID * 2);
    ushort* Wr1h    = (ushort*)alloc((size_t)HID * HID * 2);
    ushort* Wr1l    = (ushort*)alloc((size_t)HID * HID * 2);
    ushort* Wl2h    = (ushort*)alloc((size_t)HID * HID * 2);
    ushort* Wl2l    = (ushort*)alloc((size_t)HID * HID * 2);
    ushort* Wr2h    = (ushort*)alloc((size_t)HID * HID * 2);
    ushort* Wr2l    = (ushort*)alloc((size_t)HID * HID * 2);
    float*  B0      = (float*)alloc((size_t)N * HID * 4);
    float*  B1      = (float*)alloc((size_t)N * HID * 4);
    float*  B2      = (float*)alloc((size_t)N * HID * 4);

    // ---- CSR build (4-phase, no global atomics, coalesced stores) ----
    k_cnt<<<NWG, 256, 0, stream>>>(dst, E, chunk, cnt);
    k_cscan<<<1, 256, 0, stream>>>(cnt, gaddr);
    k_scatter<<<NWG, 256, 0, stream>>>(src, dst, E, chunk, gaddr, bdata);
    k_csr2<<<NBUCK, 256, 0, stream>>>(gaddr, bdata, E, csr, row_off, inv, N);

    // ---- weight packing (one launch) ----
    k_wpack_all<<<(192 * HID + 255) / 256, 256, 0, stream>>>(
        Wl0, Wr0, Wl1, Wr1, Wl2, Wr2,
        Wl0h, Wl0l, Wr0h, Wr0l, Wl1h, Wl1l, Wr1h, Wr1l, Wl2h, Wl2l, Wr2h, Wr2l);

    const int gemm_grid = N / 32;   // 3125
    const int agg_grid = N / 4;     // 25000

    // ---- layer 0: h = x (K=165, pad 192) ----
    k_gemm_mfma<IN_CH, 192><<<gemm_grid, 256, 0, stream>>>(x, Wl0h, Wl0l, Wr0h, Wr0l, B0, B1);
    k_agg2<0><<<agg_grid, 256, 0, stream>>>(B0, row_off, csr, inv, bl0, B1, B1, nullptr, nullptr, N);

    // ---- layer 1 ----
    k_gemm_mfma<HID, HID><<<gemm_grid, 256, 0, stream>>>(B1, Wl1h, Wl1l, Wr1h, Wr1l, B0, B2);
    k_agg2<0><<<agg_grid, 256, 0, stream>>>(B0, row_off, csr, inv, bl1, B2, B2, nullptr, nullptr, N);

    // ---- layer 2 + fused output head ----
    k_gemm_mfma<HID, HID><<<gemm_grid, 256, 0, stream>>>(B2, Wl2h, Wl2l, Wr2h, Wr2l, B0, B1);
    k_agg2<1><<<agg_grid, 256, 0, stream>>>(B0, row_off, csr, inv, bl2, B1, (float*)d_out, Wout, bout, N);
}

// Round 5
// 477.220 us; speedup vs baseline: 1.8664x; 1.2376x over previous
//
#include <hip/hip_runtime.h>
#include <cstdint>
#include <cstddef>

#define NN 100000
#define IN_CH 165
#define HID 128

#define NBUCK 196     // ceil(100000/512) buckets of 512 nodes (dst>>9)
#define NPB 512
#define BMAX 10240    // max edges/bucket (mean 8163, +23 sigma)
#define NWG 64        // scatter workgroups

typedef __attribute__((ext_vector_type(8))) short short8;
typedef __attribute__((ext_vector_type(4))) float f32x4;

__device__ __forceinline__ ushort f2bf(float v) {
    uint b = __builtin_bit_cast(uint, v);
    return (ushort)((b + 0x7FFFu + ((b >> 16) & 1u)) >> 16);
}
__device__ __forceinline__ float bf2f(ushort u) {
    uint b = ((uint)u) << 16;
    return __builtin_bit_cast(float, b);
}

// ================= CSR build: 4-phase bucket sort, all stores coalesced =================
__global__ __launch_bounds__(256) void k_cnt(const int* __restrict__ dst, int E, int chunk,
                                             int* __restrict__ cnt) {
    __shared__ int h[NBUCK];
    const int w = blockIdx.x, t = threadIdx.x;
    for (int b = t; b < NBUCK; b += 256) h[b] = 0;
    __syncthreads();
    const int beg = w * chunk, end = min(E, beg + chunk);
    for (int i = beg + t; i < end; i += 256) atomicAdd(&h[dst[i] >> 9], 1);
    __syncthreads();
    for (int b = t; b < NBUCK; b += 256) cnt[w * NBUCK + b] = h[b];
}

__global__ __launch_bounds__(256) void k_cscan(const int* __restrict__ cnt,
                                               int* __restrict__ gaddr) {
    __shared__ int ps[256];
    const int t = threadIdx.x;           // 12544 = 256 * 49
    int s = 0;
    for (int k = 0; k < 49; k++) {
        const int m = t * 49 + k;
        s += cnt[(m & 63) * NBUCK + (m >> 6)];
    }
    ps[t] = s;
    __syncthreads();
    for (int off = 1; off < 256; off <<= 1) {
        int v = (t >= off) ? ps[t - off] : 0;
        __syncthreads();
        ps[t] += v;
        __syncthreads();
    }
    int run = (t > 0) ? ps[t - 1] : 0;
    for (int k = 0; k < 49; k++) {
        const int m = t * 49 + k;
        gaddr[m] = run;
        run += cnt[(m & 63) * NBUCK + (m >> 6)];
    }
}

__global__ __launch_bounds__(256) void k_scatter(const int* __restrict__ src,
                                                 const int* __restrict__ dst, int E, int chunk,
                                                 const int* __restrict__ gaddr,
                                                 int* __restrict__ bdata) {
    __shared__ int cur[NBUCK];
    __shared__ int thist[256];
    __shared__ int sA[256];
    __shared__ int tex[NBUCK];
    __shared__ int lpos[NBUCK];
    __shared__ int staged[2048];
    __shared__ int addrs[2048];
    const int w = blockIdx.x, t = threadIdx.x;
    for (int b = t; b < NBUCK; b += 256) cur[b] = gaddr[b * NWG + w];
    const int beg = w * chunk, end = min(E, beg + chunk);
    for (int tb = beg; tb < end; tb += 2048) {
        const int tcnt = min(2048, end - tb);
        int key[8], bk[8];
#pragma unroll
        for (int j = 0; j < 8; j++) {
            const int i = tb + j * 256 + t;
            if (i < end) {
                const int d = dst[i];
                bk[j] = d >> 9;
                key[j] = (src[i] << 9) | (d & 511);
            } else bk[j] = -1;
        }
        __syncthreads();
        thist[t] = 0;
        __syncthreads();
#pragma unroll
        for (int j = 0; j < 8; j++)
            if (bk[j] >= 0) atomicAdd(&thist[bk[j]], 1);
        __syncthreads();
        sA[t] = thist[t];
        __syncthreads();
        for (int off = 1; off < 256; off <<= 1) {
            int v = (t >= off) ? sA[t - off] : 0;
            __syncthreads();
            sA[t] += v;
            __syncthreads();
        }
        if (t < NBUCK) {
            const int e = sA[t] - thist[t];
            tex[t] = e;
            lpos[t] = e;
        }
        __syncthreads();
#pragma unroll
        for (int j = 0; j < 8; j++)
            if (bk[j] >= 0) {
                const int b = bk[j];
                const int l = atomicAdd(&lpos[b], 1);
                staged[l] = key[j];
                addrs[l] = cur[b] + (l - tex[b]);
            }
        __syncthreads();
        for (int l = t; l < tcnt; l += 256) bdata[addrs[l]] = staged[l];
        __syncthreads();
        if (t < NBUCK) cur[t] += thist[t];
    }
}

__global__ __launch_bounds__(256) void k_csr2(const int* __restrict__ gaddr,
                                              const int* __restrict__ bdata, int E,
                                              int* __restrict__ csr, int* __restrict__ row_off,
                                              float* __restrict__ inv, int N) {
    __shared__ int keys[BMAX];
    __shared__ int sorted[BMAX];
    __shared__ int h5[NPB];
    __shared__ int s5[NPB];
    const int b = blockIdx.x, t = threadIdx.x;
    const int base = gaddr[b * NWG];
    const int nxt = (b == NBUCK - 1) ? E : gaddr[(b + 1) * NWG];
    const int tot = min(nxt - base, BMAX);
    for (int i = t; i < tot; i += 256) keys[i] = bdata[base + i];
    h5[t] = 0;
    h5[t + 256] = 0;
    __syncthreads();
    for (int i = t; i < tot; i += 256) atomicAdd(&h5[keys[i] & 511], 1);
    __syncthreads();
    s5[t] = h5[t];
    s5[t + 256] = h5[t + 256];
    __syncthreads();
    for (int off = 1; off < 512; off <<= 1) {
        const int a = (t >= off) ? s5[t - off] : 0;
        const int c = (t + 256 >= off) ? s5[t + 256 - off] : 0;
        __syncthreads();
        s5[t] += a;
        s5[t + 256] += c;
        __syncthreads();
    }
    const int e0 = s5[t] - h5[t];
    const int e1 = s5[t + 256] - h5[t + 256];
    __syncthreads();
    s5[t] = e0;
    s5[t + 256] = e1;
    const int n0 = b * NPB + t, n1 = b * NPB + t + 256;
    if (n0 < N) { row_off[n0] = base + e0; inv[n0] = 1.0f / (float)max(h5[t], 1); }
    if (n1 < N) { row_off[n1] = base + e1; inv[n1] = 1.0f / (float)max(h5[t + 256], 1); }
    if (b == 0 && t == 0) row_off[N] = E;
    __syncthreads();
    for (int i = t; i < tot; i += 256) {
        const int k = keys[i];
        const int p = atomicAdd(&s5[k & 511], 1);
        sorted[p] = k;
    }
    __syncthreads();
    for (int i = t; i < tot; i += 256) csr[base + i] = sorted[i] >> 9;
}

// ================= weight pack (all 6 matrices in one launch) =================
__device__ __forceinline__ void wpack_one(const float* __restrict__ W, int K, int idx,
                                          ushort* __restrict__ Wh, ushort* __restrict__ Wl) {
    const int k = idx >> 7;
    const int j = idx & 127;
    const float v = (k < K) ? W[j * K + k] : 0.0f;
    const ushort h = f2bf(v);
    const ushort l = f2bf(v - bf2f(h));
    const int o = (k >> 3) * (HID * 8) + j * 8 + (k & 7);
    Wh[o] = h;
    Wl[o] = l;
}

__global__ void k_wpack_all(const float* __restrict__ Wl0, const float* __restrict__ Wr0,
                            const float* __restrict__ Wl1, const float* __restrict__ Wr1,
                            const float* __restrict__ Wl2, const float* __restrict__ Wr2,
                            ushort* __restrict__ Wl0h, ushort* __restrict__ Wl0l,
                            ushort* __restrict__ Wr0h, ushort* __restrict__ Wr0l,
                            ushort* __restrict__ Wl1h, ushort* __restrict__ Wl1l,
                            ushort* __restrict__ Wr1h, ushort* __restrict__ Wr1l,
                            ushort* __restrict__ Wl2h, ushort* __restrict__ Wl2l,
                            ushort* __restrict__ Wr2h, ushort* __restrict__ Wr2l) {
    const int gid = blockIdx.x * blockDim.x + threadIdx.x;
    if (gid < 192 * HID) {
        wpack_one(Wl0, IN_CH, gid, Wl0h, Wl0l);
        wpack_one(Wr0, IN_CH, gid, Wr0h, Wr0l);
    }
    if (gid < 128 * HID) {
        wpack_one(Wl1, HID, gid, Wl1h, Wl1l);
        wpack_one(Wr1, HID, gid, Wr1h, Wr1l);
        wpack_one(Wl2, HID, gid, Wl2h, Wl2l);
        wpack_one(Wr2, HID, gid, Wr2h, Wr2l);
    }
}

// ================= MFMA dual GEMM (bf16x3 split fp32) =================
// yl (the gathered message) is written as bf16; yr (residual path) stays fp32.
template <int K, int KP>
__global__ __launch_bounds__(256) void k_gemm_mfma(
    const float* __restrict__ h,
    const ushort* __restrict__ Wlh, const ushort* __restrict__ Wll,
    const ushort* __restrict__ Wrh, const ushort* __restrict__ Wrl,
    ushort* __restrict__ yl, float* __restrict__ yr)
{
    constexpr int RS = KP * 2;  // LDS row stride (bytes)
    __shared__ __align__(16) char Ah[32 * RS];
    __shared__ __align__(16) char Al[32 * RS];
    const int tid = threadIdx.x;
    const int node0 = blockIdx.x * 32;
    const float* __restrict__ hp = h + (size_t)node0 * K;

    constexpr int Q = 32 * (KP / 4);
    for (int q = tid; q < Q; q += 256) {
        const int r = q / (KP / 4);
        const int kp = (q - r * (KP / 4)) * 4;
        float v0, v1, v2, v3;
        if constexpr (K % 4 == 0) {
            const float4 v = *reinterpret_cast<const float4*>(&hp[r * K + kp]);
            v0 = v.x; v1 = v.y; v2 = v.z; v3 = v.w;
        } else {
            v0 = (kp + 0 < K) ? hp[r * K + kp + 0] : 0.0f;
            v1 = (kp + 1 < K) ? hp[r * K + kp + 1] : 0.0f;
            v2 = (kp + 2 < K) ? hp[r * K + kp + 2] : 0.0f;
            v3 = (kp + 3 < K) ? hp[r * K + kp + 3] : 0.0f;
        }
        const ushort h0 = f2bf(v0), h1 = f2bf(v1), h2 = f2bf(v2), h3 = f2bf(v3);
        const ushort l0 = f2bf(v0 - bf2f(h0)), l1 = f2bf(v1 - bf2f(h1));
        const ushort l2 = f2bf(v2 - bf2f(h2)), l3 = f2bf(v3 - bf2f(h3));
        const int byte = r * RS + ((kp * 2) ^ ((r & 7) << 4));
        *reinterpret_cast<ushort4*>(Ah + byte) = make_ushort4(h0, h1, h2, h3);
        *reinterpret_cast<ushort4*>(Al + byte) = make_ushort4(l0, l1, l2, l3);
    }
    __syncthreads();

    const int lane = tid & 63;
    const int w = tid >> 6;
    const int trow = lane & 15;
    const int kg = lane >> 4;
    const ushort* __restrict__ Bh = (w & 1) ? Wrh : Wlh;
    const ushort* __restrict__ Bl = (w & 1) ? Wrl : Wll;
    const int cb0 = (w >> 1) * 4;

    f32x4 acc[2][4];
#pragma unroll
    for (int a = 0; a < 2; ++a)
#pragma unroll
        for (int b = 0; b < 4; ++b) acc[a][b] = (f32x4){0.f, 0.f, 0.f, 0.f};

    const int xo = (trow & 7) << 4;
    const char* __restrict__ pA0 = Ah + trow * RS;
    const char* __restrict__ pA1 = Ah + (trow + 16) * RS;
    const char* __restrict__ pL0 = Al + trow * RS;
    const char* __restrict__ pL1 = Al + (trow + 16) * RS;

    constexpr int KS = KP / 32;
    for (int ks = 0; ks < KS; ++ks) {
        const int kbyte = (ks * 64 + kg * 16) ^ xo;
        const short8 a0h = *reinterpret_cast<const short8*>(pA0 + kbyte);
        const short8 a0l = *reinterpret_cast<const short8*>(pL0 + kbyte);
        const short8 a1h = *reinterpret_cast<const short8*>(pA1 + kbyte);
        const short8 a1l = *reinterpret_cast<const short8*>(pL1 + kbyte);
        const int bbase = (ks * 4 + kg) * (HID * 8) + trow * 8;
#pragma unroll
        for (int ci = 0; ci < 4; ++ci) {
            const int bo = bbase + (cb0 + ci) * 128;
            const short8 bh = *reinterpret_cast<const short8*>(Bh + bo);
            const short8 bl = *reinterpret_cast<const short8*>(Bl + bo);
            acc[0][ci] = __builtin_amdgcn_mfma_f32_16x16x32_bf16(a0l, bh, acc[0][ci], 0, 0, 0);
            acc[0][ci] = __builtin_amdgcn_mfma_f32_16x16x32_bf16(a0h, bl, acc[0][ci], 0, 0, 0);
            acc[0][ci] = __builtin_amdgcn_mfma_f32_16x16x32_bf16(a0h, bh, acc[0][ci], 0, 0, 0);
            acc[1][ci] = __builtin_amdgcn_mfma_f32_16x16x32_bf16(a1l, bh, acc[1][ci], 0, 0, 0);
            acc[1][ci] = __builtin_amdgcn_mfma_f32_16x16x32_bf16(a1h, bl, acc[1][ci], 0, 0, 0);
            acc[1][ci] = __builtin_amdgcn_mfma_f32_16x16x32_bf16(a1h, bh, acc[1][ci], 0, 0, 0);
        }
    }

#pragma unroll
    for (int rb = 0; rb < 2; ++rb) {
        const int nb_ = node0 + rb * 16 + kg * 4;
#pragma unroll
        for (int ci = 0; ci < 4; ++ci) {
            const int col = (cb0 + ci) * 16 + trow;
            const f32x4 a = acc[rb][ci];
            if (w & 1) {
#pragma unroll
                for (int rr = 0; rr < 4; ++rr)
                    yr[(size_t)(nb_ + rr) * HID + col] = a[rr];
            } else {
#pragma unroll
                for (int rr = 0; rr < 4; ++rr)
                    yl[(size_t)(nb_ + rr) * HID + col] = f2bf(a[rr]);
            }
        }
    }
}

// ================= aggregate + combine; wave per node; bf16 message gather =================
template <int HEAD>
__global__ __launch_bounds__(256) void k_agg2(
    const ushort* __restrict__ yl, const int* __restrict__ row_off,
    const int* __restrict__ csr, const float* __restrict__ inv,
    const float* __restrict__ bias, const float* __restrict__ yr,
    float* __restrict__ outp, const float* __restrict__ Wout,
    const float* __restrict__ bout, int N)
{
    const int wid = (blockIdx.x * 256 + (int)threadIdx.x) >> 6;
    const int lane = threadIdx.x & 63;
    if (wid >= N) return;
    const int beg = row_off[wid];
    const int end = row_off[wid + 1];
    const uint* __restrict__ Y = (const uint*)yl;   // 64 uints per row (2 bf16 each)
    float ax0 = 0.f, ay0 = 0.f, ax1 = 0.f, ay1 = 0.f;
    float ax2 = 0.f, ay2 = 0.f, ax3 = 0.f, ay3 = 0.f;
    int e = beg;
    for (; e + 4 <= end; e += 4) {
        const int s0 = csr[e + 0], s1 = csr[e + 1], s2 = csr[e + 2], s3 = csr[e + 3];
        const uint u0 = Y[(size_t)s0 * 64 + lane];
        const uint u1 = Y[(size_t)s1 * 64 + lane];
        const uint u2 = Y[(size_t)s2 * 64 + lane];
        const uint u3 = Y[(size_t)s3 * 64 + lane];
        ax0 += __builtin_bit_cast(float, u0 << 16);
        ay0 += __builtin_bit_cast(float, u0 & 0xFFFF0000u);
        ax1 += __builtin_bit_cast(float, u1 << 16);
        ay1 += __builtin_bit_cast(float, u1 & 0xFFFF0000u);
        ax2 += __builtin_bit_cast(float, u2 << 16);
        ay2 += __builtin_bit_cast(float, u2 & 0xFFFF0000u);
        ax3 += __builtin_bit_cast(float, u3 << 16);
        ay3 += __builtin_bit_cast(float, u3 & 0xFFFF0000u);
    }
    for (; e < end; ++e) {
        const uint u = Y[(size_t)csr[e] * 64 + lane];
        ax0 += __builtin_bit_cast(float, u << 16);
        ay0 += __builtin_bit_cast(float, u & 0xFFFF0000u);
    }
    const float iv = inv[wid];
    const float2 r = ((const float2*)yr)[(size_t)wid * 64 + lane];
    const float2 b = ((const float2*)bias)[lane];
    float vx = (ax0 + ax1 + ax2 + ax3) * iv + b.x + r.x;
    float vy = (ay0 + ay1 + ay2 + ay3) * iv + b.y + r.y;
    if constexpr (!HEAD) {
        vx = fmaxf(vx, 0.0f);
        vy = fmaxf(vy, 0.0f);
        ((float2*)outp)[(size_t)wid * 64 + lane] = make_float2(vx, vy);
    } else {
        float p0 = vx * Wout[2 * lane] + vy * Wout[2 * lane + 1];
        float p1 = vx * Wout[128 + 2 * lane] + vy * Wout[129 + 2 * lane];
#pragma unroll
        for (int off = 32; off > 0; off >>= 1) {
            p0 += __shfl_xor(p0, off);
            p1 += __shfl_xor(p1, off);
        }
        if (lane == 0) {
            outp[(size_t)wid * 2 + 0] = p0 + bout[0];
            outp[(size_t)wid * 2 + 1] = p1 + bout[1];
        }
    }
}

extern "C" void kernel_launch(void* const* d_in, const int* in_sizes, int n_in,
                              void* d_out, int out_size, void* d_ws, size_t ws_size,
                              hipStream_t stream) {
    const float* x    = (const float*)d_in[0];
    const int*   ei   = (const int*)d_in[1];
    const float* Wl0  = (const float*)d_in[2];
    const float* bl0  = (const float*)d_in[3];
    const float* Wr0  = (const float*)d_in[4];
    const float* Wl1  = (const float*)d_in[5];
    const float* bl1  = (const float*)d_in[6];
    const float* Wr1  = (const float*)d_in[7];
    const float* Wl2  = (const float*)d_in[8];
    const float* bl2  = (const float*)d_in[9];
    const float* Wr2  = (const float*)d_in[10];
    const float* Wout = (const float*)d_in[11];
    const float* bout = (const float*)d_in[12];

    const int N = NN;
    const int E = in_sizes[1] / 2;
    const int* src = ei;
    const int* dst = ei + E;
    const int chunk = (E + NWG - 1) / NWG;

    // workspace carve-up (256B aligned)
    char* w = (char*)d_ws;
    auto alloc = [&](size_t bytes) {
        char* p = w;
        w += (bytes + 255) & ~(size_t)255;
        return p;
    };
    int*    cnt     = (int*)alloc((size_t)NWG * NBUCK * 4);
    int*    gaddr   = (int*)alloc((size_t)NWG * NBUCK * 4);
    int*    bdata   = (int*)alloc((size_t)E * 4);
    int*    row_off = (int*)alloc((size_t)(N + 1) * 4);
    float*  inv     = (float*)alloc((size_t)N * 4);
    int*    csr     = (int*)alloc((size_t)E * 4);
    ushort* Wl0h    = (ushort*)alloc((size_t)192 * HID * 2);
    ushort* Wl0l    = (ushort*)alloc((size_t)192 * HID * 2);
    ushort* Wr0h    = (ushort*)alloc((size_t)192 * HID * 2);
    ushort* Wr0l    = (ushort*)alloc((size_t)192 * HID * 2);
    ushort* Wl1h    = (ushort*)alloc((size_t)HID * HID * 2);
    ushort* Wl1l    = (ushort*)alloc((size_t)HID * HID * 2);
    ushort* Wr1h    = (ushort*)alloc((size_t)HID * HID * 2);
    ushort* Wr1l    = (ushort*)alloc((size_t)HID * HID * 2);
    ushort* Wl2h    = (ushort*)alloc((size_t)HID * HID * 2);
    ushort* Wl2l    = (ushort*)alloc((size_t)HID * HID * 2);
    ushort* Wr2h    = (ushort*)alloc((size_t)HID * HID * 2);
    ushort* Wr2l    = (ushort*)alloc((size_t)HID * HID * 2);
    ushort* B0      = (ushort*)alloc((size_t)N * HID * 2);   // bf16 messages
    float*  B1      = (float*)alloc((size_t)N * HID * 4);
    float*  B2      = (float*)alloc((size_t)N * HID * 4);

    // ---- CSR build (4-phase, no global atomics, coalesced stores) ----
    k_cnt<<<NWG, 256, 0, stream>>>(dst, E, chunk, cnt);
    k_cscan<<<1, 256, 0, stream>>>(cnt, gaddr);
    k_scatter<<<NWG, 256, 0, stream>>>(src, dst, E, chunk, gaddr, bdata);
    k_csr2<<<NBUCK, 256, 0, stream>>>(gaddr, bdata, E, csr, row_off, inv, N);

    // ---- weight packing (one launch) ----
    k_wpack_all<<<(192 * HID + 255) / 256, 256, 0, stream>>>(
        Wl0, Wr0, Wl1, Wr1, Wl2, Wr2,
        Wl0h, Wl0l, Wr0h, Wr0l, Wl1h, Wl1l, Wr1h, Wr1l, Wl2h, Wl2l, Wr2h, Wr2l);

    const int gemm_grid = N / 32;   // 3125
    const int agg_grid = N / 4;     // 25000

    // ---- layer 0: h = x (K=165, pad 192) ----
    k_gemm_mfma<IN_CH, 192><<<gemm_grid, 256, 0, stream>>>(x, Wl0h, Wl0l, Wr0h, Wr0l, B0, B1);
    k_agg2<0><<<agg_grid, 256, 0, stream>>>(B0, row_off, csr, inv, bl0, B1, B1, nullptr, nullptr, N);

    // ---- layer 1 ----
    k_gemm_mfma<HID, HID><<<gemm_grid, 256, 0, stream>>>(B1, Wl1h, Wl1l, Wr1h, Wr1l, B0, B2);
    k_agg2<0><<<agg_grid, 256, 0, stream>>>(B0, row_off, csr, inv, bl1, B2, B2, nullptr, nullptr, N);

    // ---- layer 2 + fused output head ----
    k_gemm_mfma<HID, HID><<<gemm_grid, 256, 0, stream>>>(B2, Wl2h, Wl2l, Wr2h, Wr2l, B0, B1);
    k_agg2<1><<<agg_grid, 256, 0, stream>>>(B0, row_off, csr, inv, bl2, B1, (float*)d_out, Wout, bout, N);
}

// Round 6
// 409.331 us; speedup vs baseline: 2.1759x; 1.1659x over previous
//
#include <hip/hip_runtime.h>
#include <cstdint>
#include <cstddef>

#define NN 100000
#define IN_CH 165
#define HID 128

#define NBUCK 196     // ceil(100000/512) buckets of 512 nodes (dst>>9)
#define NPB 512
#define BMAX 10240    // max edges/bucket (mean 8163, +23 sigma)
#define NWG 256       // scatter/count workgroups

typedef __attribute__((ext_vector_type(8))) short short8;
typedef __attribute__((ext_vector_type(4))) float f32x4;

__device__ __forceinline__ ushort f2bf(float v) {
    uint b = __builtin_bit_cast(uint, v);
    return (ushort)((b + 0x7FFFu + ((b >> 16) & 1u)) >> 16);
}
__device__ __forceinline__ float bf2f(ushort u) {
    uint b = ((uint)u) << 16;
    return __builtin_bit_cast(float, b);
}

// ================= CSR build: 4-phase bucket sort, all stores coalesced =================
__global__ __launch_bounds__(256) void k_cnt(const int* __restrict__ dst, int E, int chunk,
                                             int* __restrict__ cnt) {
    __shared__ int h[NBUCK];
    const int w = blockIdx.x, t = threadIdx.x;
    for (int b = t; b < NBUCK; b += 256) h[b] = 0;
    __syncthreads();
    const int beg = w * chunk, end = min(E, beg + chunk);
    for (int i = beg + t; i < end; i += 256) atomicAdd(&h[dst[i] >> 9], 1);
    __syncthreads();
    for (int b = t; b < NBUCK; b += 256) cnt[w * NBUCK + b] = h[b];
}

// scan of the NWG x NBUCK count matrix in (b-major, w-minor) order; m = b*NWG + w
__global__ __launch_bounds__(256) void k_cscan(const int* __restrict__ cnt,
                                               int* __restrict__ gaddr) {
    __shared__ int ps[256];
    const int t = threadIdx.x;           // 50176 = 256 * 196
    int s = 0;
    for (int k = 0; k < NBUCK; k++) {
        const int m = t * NBUCK + k;
        s += cnt[(m & (NWG - 1)) * NBUCK + (m >> 8)];
    }
    ps[t] = s;
    __syncthreads();
    for (int off = 1; off < 256; off <<= 1) {
        int v = (t >= off) ? ps[t - off] : 0;
        __syncthreads();
        ps[t] += v;
        __syncthreads();
    }
    int run = (t > 0) ? ps[t - 1] : 0;
    for (int k = 0; k < NBUCK; k++) {
        const int m = t * NBUCK + k;
        gaddr[m] = run;
        run += cnt[(m & (NWG - 1)) * NBUCK + (m >> 8)];
    }
}

__global__ __launch_bounds__(256) void k_scatter(const int* __restrict__ src,
                                                 const int* __restrict__ dst, int E, int chunk,
                                                 const int* __restrict__ gaddr,
                                                 int* __restrict__ bdata) {
    __shared__ int cur[NBUCK];
    __shared__ int thist[256];
    __shared__ int sA[256];
    __shared__ int tex[NBUCK];
    __shared__ int lpos[NBUCK];
    __shared__ int staged[2048];
    __shared__ int addrs[2048];
    const int w = blockIdx.x, t = threadIdx.x;
    for (int b = t; b < NBUCK; b += 256) cur[b] = gaddr[b * NWG + w];
    const int beg = w * chunk, end = min(E, beg + chunk);
    for (int tb = beg; tb < end; tb += 2048) {
        const int tcnt = min(2048, end - tb);
        int key[8], bk[8];
#pragma unroll
        for (int j = 0; j < 8; j++) {
            const int i = tb + j * 256 + t;
            if (i < end) {
                const int d = dst[i];
                bk[j] = d >> 9;
                key[j] = (src[i] << 9) | (d & 511);
            } else bk[j] = -1;
        }
        __syncthreads();
        thist[t] = 0;
        __syncthreads();
#pragma unroll
        for (int j = 0; j < 8; j++)
            if (bk[j] >= 0) atomicAdd(&thist[bk[j]], 1);
        __syncthreads();
        sA[t] = thist[t];
        __syncthreads();
        for (int off = 1; off < 256; off <<= 1) {
            int v = (t >= off) ? sA[t - off] : 0;
            __syncthreads();
            sA[t] += v;
            __syncthreads();
        }
        if (t < NBUCK) {
            const int e = sA[t] - thist[t];
            tex[t] = e;
            lpos[t] = e;
        }
        __syncthreads();
#pragma unroll
        for (int j = 0; j < 8; j++)
            if (bk[j] >= 0) {
                const int b = bk[j];
                const int l = atomicAdd(&lpos[b], 1);
                staged[l] = key[j];
                addrs[l] = cur[b] + (l - tex[b]);
            }
        __syncthreads();
        for (int l = t; l < tcnt; l += 256) bdata[addrs[l]] = staged[l];
        __syncthreads();
        if (t < NBUCK) cur[t] += thist[t];
    }
}

__global__ __launch_bounds__(256) void k_csr2(const int* __restrict__ gaddr,
                                              const int* __restrict__ bdata, int E,
                                              int* __restrict__ csr, int* __restrict__ row_off,
                                              float* __restrict__ inv, int N) {
    __shared__ int keys[BMAX];
    __shared__ int sorted[BMAX];
    __shared__ int h5[NPB];
    __shared__ int s5[NPB];
    const int b = blockIdx.x, t = threadIdx.x;
    const int base = gaddr[b * NWG];
    const int nxt = (b == NBUCK - 1) ? E : gaddr[(b + 1) * NWG];
    const int tot = min(nxt - base, BMAX);
    for (int i = t; i < tot; i += 256) keys[i] = bdata[base + i];
    h5[t] = 0;
    h5[t + 256] = 0;
    __syncthreads();
    for (int i = t; i < tot; i += 256) atomicAdd(&h5[keys[i] & 511], 1);
    __syncthreads();
    s5[t] = h5[t];
    s5[t + 256] = h5[t + 256];
    __syncthreads();
    for (int off = 1; off < 512; off <<= 1) {
        const int a = (t >= off) ? s5[t - off] : 0;
        const int c = (t + 256 >= off) ? s5[t + 256 - off] : 0;
        __syncthreads();
        s5[t] += a;
        s5[t + 256] += c;
        __syncthreads();
    }
    const int e0 = s5[t] - h5[t];
    const int e1 = s5[t + 256] - h5[t + 256];
    __syncthreads();
    s5[t] = e0;
    s5[t + 256] = e1;
    const int n0 = b * NPB + t, n1 = b * NPB + t + 256;
    if (n0 < N) { row_off[n0] = base + e0; inv[n0] = 1.0f / (float)max(h5[t], 1); }
    if (n1 < N) { row_off[n1] = base + e1; inv[n1] = 1.0f / (float)max(h5[t + 256], 1); }
    if (b == 0 && t == 0) row_off[N] = E;
    __syncthreads();
    for (int i = t; i < tot; i += 256) {
        const int k = keys[i];
        const int p = atomicAdd(&s5[k & 511], 1);
        sorted[p] = k;
    }
    __syncthreads();
    for (int i = t; i < tot; i += 256) csr[base + i] = sorted[i] >> 9;
}

// ================= weight pack (bf16 hi only, k-blocked) =================
// layout: out[(k>>3)*1024 + j*8 + (k&7)], zero-padded to KP
__device__ __forceinline__ void wpack_one(const float* __restrict__ W, int K, int idx,
                                          ushort* __restrict__ Wh) {
    const int k = idx >> 7;
    const int j = idx & 127;
    const float v = (k < K) ? W[j * K + k] : 0.0f;
    const int o = (k >> 3) * (HID * 8) + j * 8 + (k & 7);
    Wh[o] = f2bf(v);
}

__global__ void k_wpack_all(const float* __restrict__ Wl0, const float* __restrict__ Wr0,
                            const float* __restrict__ Wl1, const float* __restrict__ Wr1,
                            const float* __restrict__ Wl2, const float* __restrict__ Wr2,
                            ushort* __restrict__ Wl0h, ushort* __restrict__ Wr0h,
                            ushort* __restrict__ Wl1h, ushort* __restrict__ Wr1h,
                            ushort* __restrict__ Wl2h, ushort* __restrict__ Wr2h) {
    const int gid = blockIdx.x * blockDim.x + threadIdx.x;
    if (gid < 192 * HID) {
        wpack_one(Wl0, IN_CH, gid, Wl0h);
        wpack_one(Wr0, IN_CH, gid, Wr0h);
    }
    if (gid < 128 * HID) {
        wpack_one(Wl1, HID, gid, Wl1h);
        wpack_one(Wr1, HID, gid, Wr1h);
        wpack_one(Wl2, HID, gid, Wl2h);
        wpack_one(Wr2, HID, gid, Wr2h);
    }
}

// ================= MFMA dual GEMM (pure bf16) =================
// yl (the gathered message) is written as bf16; yr (residual path) stays fp32.
template <int K, int KP>
__global__ __launch_bounds__(256) void k_gemm_mfma(
    const float* __restrict__ h,
    const ushort* __restrict__ Wlh, const ushort* __restrict__ Wrh,
    ushort* __restrict__ yl, float* __restrict__ yr)
{
    constexpr int RS = KP * 2;  // LDS row stride (bytes)
    __shared__ __align__(16) char Ah[32 * RS];
    const int tid = threadIdx.x;
    const int node0 = blockIdx.x * 32;
    const float* __restrict__ hp = h + (size_t)node0 * K;

    constexpr int Q = 32 * (KP / 4);
    for (int q = tid; q < Q; q += 256) {
        const int r = q / (KP / 4);
        const int kp = (q - r * (KP / 4)) * 4;
        float v0, v1, v2, v3;
        if constexpr (K % 4 == 0) {
            const float4 v = *reinterpret_cast<const float4*>(&hp[r * K + kp]);
            v0 = v.x; v1 = v.y; v2 = v.z; v3 = v.w;
        } else {
            v0 = (kp + 0 < K) ? hp[r * K + kp + 0] : 0.0f;
            v1 = (kp + 1 < K) ? hp[r * K + kp + 1] : 0.0f;
            v2 = (kp + 2 < K) ? hp[r * K + kp + 2] : 0.0f;
            v3 = (kp + 3 < K) ? hp[r * K + kp + 3] : 0.0f;
        }
        const int byte = r * RS + ((kp * 2) ^ ((r & 7) << 4));
        *reinterpret_cast<ushort4*>(Ah + byte) =
            make_ushort4(f2bf(v0), f2bf(v1), f2bf(v2), f2bf(v3));
    }
    __syncthreads();

    const int lane = tid & 63;
    const int w = tid >> 6;
    const int trow = lane & 15;
    const int kg = lane >> 4;
    const ushort* __restrict__ Bh = (w & 1) ? Wrh : Wlh;
    const int cb0 = (w >> 1) * 4;

    f32x4 acc[2][4];
#pragma unroll
    for (int a = 0; a < 2; ++a)
#pragma unroll
        for (int b = 0; b < 4; ++b) acc[a][b] = (f32x4){0.f, 0.f, 0.f, 0.f};

    const int xo = (trow & 7) << 4;
    const char* __restrict__ pA0 = Ah + trow * RS;
    const char* __restrict__ pA1 = Ah + (trow + 16) * RS;

    constexpr int KS = KP / 32;
    for (int ks = 0; ks < KS; ++ks) {
        const int kbyte = (ks * 64 + kg * 16) ^ xo;
        const short8 a0h = *reinterpret_cast<const short8*>(pA0 + kbyte);
        const short8 a1h = *reinterpret_cast<const short8*>(pA1 + kbyte);
        const int bbase = (ks * 4 + kg) * (HID * 8) + trow * 8;
#pragma unroll
        for (int ci = 0; ci < 4; ++ci) {
            const short8 bh = *reinterpret_cast<const short8*>(Bh + bbase + (cb0 + ci) * 128);
            acc[0][ci] = __builtin_amdgcn_mfma_f32_16x16x32_bf16(a0h, bh, acc[0][ci], 0, 0, 0);
            acc[1][ci] = __builtin_amdgcn_mfma_f32_16x16x32_bf16(a1h, bh, acc[1][ci], 0, 0, 0);
        }
    }

#pragma unroll
    for (int rb = 0; rb < 2; ++rb) {
        const int nb_ = node0 + rb * 16 + kg * 4;
#pragma unroll
        for (int ci = 0; ci < 4; ++ci) {
            const int col = (cb0 + ci) * 16 + trow;
            const f32x4 a = acc[rb][ci];
            if (w & 1) {
#pragma unroll
                for (int rr = 0; rr < 4; ++rr)
                    yr[(size_t)(nb_ + rr) * HID + col] = a[rr];
            } else {
#pragma unroll
                for (int rr = 0; rr < 4; ++rr)
                    yl[(size_t)(nb_ + rr) * HID + col] = f2bf(a[rr]);
            }
        }
    }
}

// ================= aggregate + combine; wave per node; bf16 message gather =================
template <int HEAD>
__global__ __launch_bounds__(256) void k_agg2(
    const ushort* __restrict__ yl, const int* __restrict__ row_off,
    const int* __restrict__ csr, const float* __restrict__ inv,
    const float* __restrict__ bias, const float* __restrict__ yr,
    float* __restrict__ outp, const float* __restrict__ Wout,
    const float* __restrict__ bout, int N)
{
    const int wid = (blockIdx.x * 256 + (int)threadIdx.x) >> 6;
    const int lane = threadIdx.x & 63;
    if (wid >= N) return;
    const int beg = row_off[wid];
    const int end = row_off[wid + 1];
    const uint* __restrict__ Y = (const uint*)yl;   // 64 uints per row (2 bf16 each)
    float ax = 0.f, ay = 0.f;
    int e = beg;
    for (; e + 8 <= end; e += 8) {
        int s[8];
#pragma unroll
        for (int j = 0; j < 8; j++) s[j] = csr[e + j];
        uint u[8];
#pragma unroll
        for (int j = 0; j < 8; j++) u[j] = Y[(size_t)s[j] * 64 + lane];
#pragma unroll
        for (int j = 0; j < 8; j++) {
            ax += __builtin_bit_cast(float, u[j] << 16);
            ay += __builtin_bit_cast(float, u[j] & 0xFFFF0000u);
        }
    }
    for (; e + 2 <= end; e += 2) {
        const uint u0 = Y[(size_t)csr[e] * 64 + lane];
        const uint u1 = Y[(size_t)csr[e + 1] * 64 + lane];
        ax += __builtin_bit_cast(float, u0 << 16) + __builtin_bit_cast(float, u1 << 16);
        ay += __builtin_bit_cast(float, u0 & 0xFFFF0000u) +
              __builtin_bit_cast(float, u1 & 0xFFFF0000u);
    }
    if (e < end) {
        const uint u = Y[(size_t)csr[e] * 64 + lane];
        ax += __builtin_bit_cast(float, u << 16);
        ay += __builtin_bit_cast(float, u & 0xFFFF0000u);
    }
    const float iv = inv[wid];
    const float2 r = ((const float2*)yr)[(size_t)wid * 64 + lane];
    const float2 b = ((const float2*)bias)[lane];
    float vx = ax * iv + b.x + r.x;
    float vy = ay * iv + b.y + r.y;
    if constexpr (!HEAD) {
        vx = fmaxf(vx, 0.0f);
        vy = fmaxf(vy, 0.0f);
        ((float2*)outp)[(size_t)wid * 64 + lane] = make_float2(vx, vy);
    } else {
        float p0 = vx * Wout[2 * lane] + vy * Wout[2 * lane + 1];
        float p1 = vx * Wout[128 + 2 * lane] + vy * Wout[129 + 2 * lane];
#pragma unroll
        for (int off = 32; off > 0; off >>= 1) {
            p0 += __shfl_xor(p0, off);
            p1 += __shfl_xor(p1, off);
        }
        if (lane == 0) {
            outp[(size_t)wid * 2 + 0] = p0 + bout[0];
            outp[(size_t)wid * 2 + 1] = p1 + bout[1];
        }
    }
}

extern "C" void kernel_launch(void* const* d_in, const int* in_sizes, int n_in,
                              void* d_out, int out_size, void* d_ws, size_t ws_size,
                              hipStream_t stream) {
    const float* x    = (const float*)d_in[0];
    const int*   ei   = (const int*)d_in[1];
    const float* Wl0  = (const float*)d_in[2];
    const float* bl0  = (const float*)d_in[3];
    const float* Wr0  = (const float*)d_in[4];
    const float* Wl1  = (const float*)d_in[5];
    const float* bl1  = (const float*)d_in[6];
    const float* Wr1  = (const float*)d_in[7];
    const float* Wl2  = (const float*)d_in[8];
    const float* bl2  = (const float*)d_in[9];
    const float* Wr2  = (const float*)d_in[10];
    const float* Wout = (const float*)d_in[11];
    const float* bout = (const float*)d_in[12];

    const int N = NN;
    const int E = in_sizes[1] / 2;
    const int* src = ei;
    const int* dst = ei + E;
    const int chunk = (E + NWG - 1) / NWG;

    // workspace carve-up (256B aligned)
    char* w = (char*)d_ws;
    auto alloc = [&](size_t bytes) {
        char* p = w;
        w += (bytes + 255) & ~(size_t)255;
        return p;
    };
    int*    cnt     = (int*)alloc((size_t)NWG * NBUCK * 4);
    int*    gaddr   = (int*)alloc((size_t)NWG * NBUCK * 4);
    int*    bdata   = (int*)alloc((size_t)E * 4);
    int*    row_off = (int*)alloc((size_t)(N + 1) * 4);
    float*  inv     = (float*)alloc((size_t)N * 4);
    int*    csr     = (int*)alloc((size_t)E * 4);
    ushort* Wl0h    = (ushort*)alloc((size_t)192 * HID * 2);
    ushort* Wr0h    = (ushort*)alloc((size_t)192 * HID * 2);
    ushort* Wl1h    = (ushort*)alloc((size_t)HID * HID * 2);
    ushort* Wr1h    = (ushort*)alloc((size_t)HID * HID * 2);
    ushort* Wl2h    = (ushort*)alloc((size_t)HID * HID * 2);
    ushort* Wr2h    = (ushort*)alloc((size_t)HID * HID * 2);
    ushort* B0      = (ushort*)alloc((size_t)N * HID * 2);   // bf16 messages
    float*  B1      = (float*)alloc((size_t)N * HID * 4);
    float*  B2      = (float*)alloc((size_t)N * HID * 4);

    // ---- CSR build (4-phase, no global atomics, coalesced stores) ----
    k_cnt<<<NWG, 256, 0, stream>>>(dst, E, chunk, cnt);
    k_cscan<<<1, 256, 0, stream>>>(cnt, gaddr);
    k_scatter<<<NWG, 256, 0, stream>>>(src, dst, E, chunk, gaddr, bdata);
    k_csr2<<<NBUCK, 256, 0, stream>>>(gaddr, bdata, E, csr, row_off, inv, N);

    // ---- weight packing (one launch, hi planes only) ----
    k_wpack_all<<<(192 * HID + 255) / 256, 256, 0, stream>>>(
        Wl0, Wr0, Wl1, Wr1, Wl2, Wr2, Wl0h, Wr0h, Wl1h, Wr1h, Wl2h, Wr2h);

    const int gemm_grid = N / 32;   // 3125
    const int agg_grid = N / 4;     // 25000

    // ---- layer 0: h = x (K=165, pad 192) ----
    k_gemm_mfma<IN_CH, 192><<<gemm_grid, 256, 0, stream>>>(x, Wl0h, Wr0h, B0, B1);
    k_agg2<0><<<agg_grid, 256, 0, stream>>>(B0, row_off, csr, inv, bl0, B1, B1, nullptr, nullptr, N);

    // ---- layer 1 ----
    k_gemm_mfma<HID, HID><<<gemm_grid, 256, 0, stream>>>(B1, Wl1h, Wr1h, B0, B2);
    k_agg2<0><<<agg_grid, 256, 0, stream>>>(B0, row_off, csr, inv, bl1, B2, B2, nullptr, nullptr, N);

    // ---- layer 2 + fused output head ----
    k_gemm_mfma<HID, HID><<<gemm_grid, 256, 0, stream>>>(B2, Wl2h, Wr2h, B0, B1);
    k_agg2<1><<<agg_grid, 256, 0, stream>>>(B0, row_off, csr, inv, bl2, B1, (float*)d_out, Wout, bout, N);
}

// Round 7
// 385.108 us; speedup vs baseline: 2.3128x; 1.0629x over previous
//
#include <hip/hip_runtime.h>
#include <cstdint>
#include <cstddef>

#define NN 100000
#define IN_CH 165
#define HID 128

#define NBUCK 196     // ceil(100000/512) buckets of 512 nodes (dst>>9)
#define NPB 512
#define BMAX 10240    // max edges/bucket (mean 8163, +23 sigma)
#define NWG 256       // scatter/count workgroups

typedef __attribute__((ext_vector_type(8))) short short8;
typedef __attribute__((ext_vector_type(4))) float f32x4;

__device__ __forceinline__ ushort f2bf(float v) {
    uint b = __builtin_bit_cast(uint, v);
    return (ushort)((b + 0x7FFFu + ((b >> 16) & 1u)) >> 16);
}
__device__ __forceinline__ float bf2f(ushort u) {
    uint b = ((uint)u) << 16;
    return __builtin_bit_cast(float, b);
}
__device__ __forceinline__ float lo16f(uint u) { return __builtin_bit_cast(float, u << 16); }
__device__ __forceinline__ float hi16f(uint u) { return __builtin_bit_cast(float, u & 0xFFFF0000u); }

// ================= CSR build: 4-phase bucket sort, all stores coalesced =================
__global__ __launch_bounds__(256) void k_cnt(const int* __restrict__ dst, int E, int chunk,
                                             int* __restrict__ cnt) {
    __shared__ int h[NBUCK];
    const int w = blockIdx.x, t = threadIdx.x;
    for (int b = t; b < NBUCK; b += 256) h[b] = 0;
    __syncthreads();
    const int beg = w * chunk, end = min(E, beg + chunk);
    for (int i = beg + t; i < end; i += 256) atomicAdd(&h[dst[i] >> 9], 1);
    __syncthreads();
    for (int b = t; b < NBUCK; b += 256) cnt[w * NBUCK + b] = h[b];
}

// scan of the NWG x NBUCK count matrix in (b-major, w-minor) order; m = b*NWG + w
__global__ __launch_bounds__(256) void k_cscan(const int* __restrict__ cnt,
                                               int* __restrict__ gaddr) {
    __shared__ int ps[256];
    const int t = threadIdx.x;           // 50176 = 256 * 196
    int s = 0;
    for (int k = 0; k < NBUCK; k++) {
        const int m = t * NBUCK + k;
        s += cnt[(m & (NWG - 1)) * NBUCK + (m >> 8)];
    }
    ps[t] = s;
    __syncthreads();
    for (int off = 1; off < 256; off <<= 1) {
        int v = (t >= off) ? ps[t - off] : 0;
        __syncthreads();
        ps[t] += v;
        __syncthreads();
    }
    int run = (t > 0) ? ps[t - 1] : 0;
    for (int k = 0; k < NBUCK; k++) {
        const int m = t * NBUCK + k;
        gaddr[m] = run;
        run += cnt[(m & (NWG - 1)) * NBUCK + (m >> 8)];
    }
}

__global__ __launch_bounds__(256) void k_scatter(const int* __restrict__ src,
                                                 const int* __restrict__ dst, int E, int chunk,
                                                 const int* __restrict__ gaddr,
                                                 int* __restrict__ bdata) {
    __shared__ int cur[NBUCK];
    __shared__ int thist[256];
    __shared__ int sA[256];
    __shared__ int tex[NBUCK];
    __shared__ int lpos[NBUCK];
    __shared__ int staged[2048];
    __shared__ int addrs[2048];
    const int w = blockIdx.x, t = threadIdx.x;
    for (int b = t; b < NBUCK; b += 256) cur[b] = gaddr[b * NWG + w];
    const int beg = w * chunk, end = min(E, beg + chunk);
    for (int tb = beg; tb < end; tb += 2048) {
        const int tcnt = min(2048, end - tb);
        int key[8], bk[8];
#pragma unroll
        for (int j = 0; j < 8; j++) {
            const int i = tb + j * 256 + t;
            if (i < end) {
                const int d = dst[i];
                bk[j] = d >> 9;
                key[j] = (src[i] << 9) | (d & 511);
            } else bk[j] = -1;
        }
        __syncthreads();
        thist[t] = 0;
        __syncthreads();
#pragma unroll
        for (int j = 0; j < 8; j++)
            if (bk[j] >= 0) atomicAdd(&thist[bk[j]], 1);
        __syncthreads();
        sA[t] = thist[t];
        __syncthreads();
        for (int off = 1; off < 256; off <<= 1) {
            int v = (t >= off) ? sA[t - off] : 0;
            __syncthreads();
            sA[t] += v;
            __syncthreads();
        }
        if (t < NBUCK) {
            const int e = sA[t] - thist[t];
            tex[t] = e;
            lpos[t] = e;
        }
        __syncthreads();
#pragma unroll
        for (int j = 0; j < 8; j++)
            if (bk[j] >= 0) {
                const int b = bk[j];
                const int l = atomicAdd(&lpos[b], 1);
                staged[l] = key[j];
                addrs[l] = cur[b] + (l - tex[b]);
            }
        __syncthreads();
        for (int l = t; l < tcnt; l += 256) bdata[addrs[l]] = staged[l];
        __syncthreads();
        if (t < NBUCK) cur[t] += thist[t];
    }
}

__global__ __launch_bounds__(256) void k_csr2(const int* __restrict__ gaddr,
                                              const int* __restrict__ bdata, int E,
                                              int* __restrict__ csr, int* __restrict__ row_off,
                                              float* __restrict__ inv, int N) {
    __shared__ int keys[BMAX];
    __shared__ int sorted[BMAX];
    __shared__ int h5[NPB];
    __shared__ int s5[NPB];
    const int b = blockIdx.x, t = threadIdx.x;
    const int base = gaddr[b * NWG];
    const int nxt = (b == NBUCK - 1) ? E : gaddr[(b + 1) * NWG];
    const int tot = min(nxt - base, BMAX);
    for (int i = t; i < tot; i += 256) keys[i] = bdata[base + i];
    h5[t] = 0;
    h5[t + 256] = 0;
    __syncthreads();
    for (int i = t; i < tot; i += 256) atomicAdd(&h5[keys[i] & 511], 1);
    __syncthreads();
    s5[t] = h5[t];
    s5[t + 256] = h5[t + 256];
    __syncthreads();
    for (int off = 1; off < 512; off <<= 1) {
        const int a = (t >= off) ? s5[t - off] : 0;
        const int c = (t + 256 >= off) ? s5[t + 256 - off] : 0;
        __syncthreads();
        s5[t] += a;
        s5[t + 256] += c;
        __syncthreads();
    }
    const int e0 = s5[t] - h5[t];
    const int e1 = s5[t + 256] - h5[t + 256];
    __syncthreads();
    s5[t] = e0;
    s5[t + 256] = e1;
    const int n0 = b * NPB + t, n1 = b * NPB + t + 256;
    if (n0 < N) { row_off[n0] = base + e0; inv[n0] = 1.0f / (float)max(h5[t], 1); }
    if (n1 < N) { row_off[n1] = base + e1; inv[n1] = 1.0f / (float)max(h5[t + 256], 1); }
    if (b == 0 && t == 0) row_off[N] = E;
    __syncthreads();
    for (int i = t; i < tot; i += 256) {
        const int k = keys[i];
        const int p = atomicAdd(&s5[k & 511], 1);
        sorted[p] = k;
    }
    __syncthreads();
    for (int i = t; i < tot; i += 256) csr[base + i] = sorted[i] >> 9;
}

// ================= weight pack (bf16, k-blocked) =================
__device__ __forceinline__ void wpack_one(const float* __restrict__ W, int K, int idx,
                                          ushort* __restrict__ Wh) {
    const int k = idx >> 7;
    const int j = idx & 127;
    const float v = (k < K) ? W[j * K + k] : 0.0f;
    const int o = (k >> 3) * (HID * 8) + j * 8 + (k & 7);
    Wh[o] = f2bf(v);
}

__global__ void k_wpack_all(const float* __restrict__ Wl0, const float* __restrict__ Wr0,
                            const float* __restrict__ Wl1, const float* __restrict__ Wr1,
                            const float* __restrict__ Wl2, const float* __restrict__ Wr2,
                            ushort* __restrict__ Wl0h, ushort* __restrict__ Wr0h,
                            ushort* __restrict__ Wl1h, ushort* __restrict__ Wr1h,
                            ushort* __restrict__ Wl2h, ushort* __restrict__ Wr2h) {
    const int gid = blockIdx.x * blockDim.x + threadIdx.x;
    if (gid < 192 * HID) {
        wpack_one(Wl0, IN_CH, gid, Wl0h);
        wpack_one(Wr0, IN_CH, gid, Wr0h);
    }
    if (gid < 128 * HID) {
        wpack_one(Wl1, HID, gid, Wl1h);
        wpack_one(Wr1, HID, gid, Wr1h);
        wpack_one(Wl2, HID, gid, Wl2h);
        wpack_one(Wr2, HID, gid, Wr2h);
    }
}

// ================= MFMA dual GEMM (pure bf16); outputs yl, yr both bf16 =================
// TIN = float (layer 0, fp32 x) or ushort (bf16 h from agg — identical value path,
// since the fp32 variant quantizes via f2bf during staging anyway).
template <typename TIN, int K, int KP>
__global__ __launch_bounds__(256) void k_gemm_mfma(
    const TIN* __restrict__ h,
    const ushort* __restrict__ Wlh, const ushort* __restrict__ Wrh,
    ushort* __restrict__ yl, ushort* __restrict__ yr)
{
    constexpr int RS = KP * 2;  // LDS row stride (bytes)
    __shared__ __align__(16) char Ah[32 * RS];
    const int tid = threadIdx.x;
    const int node0 = blockIdx.x * 32;
    const TIN* __restrict__ hp = h + (size_t)node0 * K;

    if constexpr (sizeof(TIN) == 2) {
        // bf16 input: direct 16B copies, no conversion
        constexpr int Q = 32 * (KP / 8);
        for (int q = tid; q < Q; q += 256) {
            const int r = q / (KP / 8);
            const int kp = (q - r * (KP / 8)) * 8;
            const short8 v = *reinterpret_cast<const short8*>(&hp[r * K + kp]);
            const int byte = r * RS + ((kp * 2) ^ ((r & 7) << 4));
            *reinterpret_cast<short8*>(Ah + byte) = v;
        }
    } else {
        constexpr int Q = 32 * (KP / 4);
        for (int q = tid; q < Q; q += 256) {
            const int r = q / (KP / 4);
            const int kp = (q - r * (KP / 4)) * 4;
            float v0, v1, v2, v3;
            if constexpr (K % 4 == 0) {
                const float4 v = *reinterpret_cast<const float4*>(&hp[r * K + kp]);
                v0 = v.x; v1 = v.y; v2 = v.z; v3 = v.w;
            } else {
                v0 = (kp + 0 < K) ? hp[r * K + kp + 0] : 0.0f;
                v1 = (kp + 1 < K) ? hp[r * K + kp + 1] : 0.0f;
                v2 = (kp + 2 < K) ? hp[r * K + kp + 2] : 0.0f;
                v3 = (kp + 3 < K) ? hp[r * K + kp + 3] : 0.0f;
            }
            const int byte = r * RS + ((kp * 2) ^ ((r & 7) << 4));
            *reinterpret_cast<ushort4*>(Ah + byte) =
                make_ushort4(f2bf(v0), f2bf(v1), f2bf(v2), f2bf(v3));
        }
    }
    __syncthreads();

    const int lane = tid & 63;
    const int w = tid >> 6;
    const int trow = lane & 15;
    const int kg = lane >> 4;
    const ushort* __restrict__ Bh = (w & 1) ? Wrh : Wlh;
    ushort* __restrict__ yo = (w & 1) ? yr : yl;
    const int cb0 = (w >> 1) * 4;

    f32x4 acc[2][4];
#pragma unroll
    for (int a = 0; a < 2; ++a)
#pragma unroll
        for (int b = 0; b < 4; ++b) acc[a][b] = (f32x4){0.f, 0.f, 0.f, 0.f};

    const int xo = (trow & 7) << 4;
    const char* __restrict__ pA0 = Ah + trow * RS;
    const char* __restrict__ pA1 = Ah + (trow + 16) * RS;

    constexpr int KS = KP / 32;
    for (int ks = 0; ks < KS; ++ks) {
        const int kbyte = (ks * 64 + kg * 16) ^ xo;
        const short8 a0h = *reinterpret_cast<const short8*>(pA0 + kbyte);
        const short8 a1h = *reinterpret_cast<const short8*>(pA1 + kbyte);
        const int bbase = (ks * 4 + kg) * (HID * 8) + trow * 8;
#pragma unroll
        for (int ci = 0; ci < 4; ++ci) {
            const short8 bh = *reinterpret_cast<const short8*>(Bh + bbase + (cb0 + ci) * 128);
            acc[0][ci] = __builtin_amdgcn_mfma_f32_16x16x32_bf16(a0h, bh, acc[0][ci], 0, 0, 0);
            acc[1][ci] = __builtin_amdgcn_mfma_f32_16x16x32_bf16(a1h, bh, acc[1][ci], 0, 0, 0);
        }
    }

#pragma unroll
    for (int rb = 0; rb < 2; ++rb) {
        const int nb_ = node0 + rb * 16 + kg * 4;
#pragma unroll
        for (int ci = 0; ci < 4; ++ci) {
            const int col = (cb0 + ci) * 16 + trow;
            const f32x4 a = acc[rb][ci];
#pragma unroll
            for (int rr = 0; rr < 4; ++rr)
                yo[(size_t)(nb_ + rr) * HID + col] = f2bf(a[rr]);
        }
    }
}

// ================= aggregate + combine; wave per node, 2 edges in flight =================
// lanes 0-31 handle even edges, lanes 32-63 odd edges; uint2 (4 bf16) per lane.
// HEAD=0: h_next (bf16) = relu(mean + bias + yr);  HEAD=1: fused output head.
template <int HEAD>
__global__ __launch_bounds__(256) void k_agg2(
    const ushort* __restrict__ yl, const int* __restrict__ row_off,
    const int* __restrict__ csr, const float* __restrict__ inv,
    const float* __restrict__ bias, const ushort* __restrict__ yr,
    void* __restrict__ outp, const float* __restrict__ Wout,
    const float* __restrict__ bout, int N)
{
    const int wid = (blockIdx.x * 256 + (int)threadIdx.x) >> 6;
    const int lane = threadIdx.x & 63;
    if (wid >= N) return;
    const int half = lane >> 5;
    const int l5 = lane & 31;
    const int beg = row_off[wid];
    const int end = row_off[wid + 1];
    const uint2* __restrict__ Y = (const uint2*)yl;   // 32 uint2 per row
    float a0 = 0.f, a1 = 0.f, a2 = 0.f, a3 = 0.f;
    int e = beg;
    for (; e + 8 <= end; e += 8) {
        const int s0 = csr[e + 0 + half];
        const int s1 = csr[e + 2 + half];
        const int s2 = csr[e + 4 + half];
        const int s3 = csr[e + 6 + half];
        const uint2 u0 = Y[(size_t)s0 * 32 + l5];
        const uint2 u1 = Y[(size_t)s1 * 32 + l5];
        const uint2 u2 = Y[(size_t)s2 * 32 + l5];
        const uint2 u3 = Y[(size_t)s3 * 32 + l5];
        a0 += lo16f(u0.x) + lo16f(u1.x) + lo16f(u2.x) + lo16f(u3.x);
        a1 += hi16f(u0.x) + hi16f(u1.x) + hi16f(u2.x) + hi16f(u3.x);
        a2 += lo16f(u0.y) + lo16f(u1.y) + lo16f(u2.y) + lo16f(u3.y);
        a3 += hi16f(u0.y) + hi16f(u1.y) + hi16f(u2.y) + hi16f(u3.y);
    }
    for (; e + 2 <= end; e += 2) {
        const int s = csr[e + half];
        const uint2 u = Y[(size_t)s * 32 + l5];
        a0 += lo16f(u.x);
        a1 += hi16f(u.x);
        a2 += lo16f(u.y);
        a3 += hi16f(u.y);
    }
    if (e < end && half == 0) {
        const int s = csr[e];
        const uint2 u = Y[(size_t)s * 32 + l5];
        a0 += lo16f(u.x);
        a1 += hi16f(u.x);
        a2 += lo16f(u.y);
        a3 += hi16f(u.y);
    }
    a0 += __shfl_xor(a0, 32);
    a1 += __shfl_xor(a1, 32);
    a2 += __shfl_xor(a2, 32);
    a3 += __shfl_xor(a3, 32);

    if (lane < 32) {
        const float iv = inv[wid];
        const uint2 rv = ((const uint2*)yr)[(size_t)wid * 32 + lane];
        const float4 b = ((const float4*)bias)[lane];
        float v0 = a0 * iv + b.x + lo16f(rv.x);
        float v1 = a1 * iv + b.y + hi16f(rv.x);
        float v2 = a2 * iv + b.z + lo16f(rv.y);
        float v3 = a3 * iv + b.w + hi16f(rv.y);
        if constexpr (!HEAD) {
            v0 = fmaxf(v0, 0.0f);
            v1 = fmaxf(v1, 0.0f);
            v2 = fmaxf(v2, 0.0f);
            v3 = fmaxf(v3, 0.0f);
            uint2 o;
            o.x = (uint)f2bf(v0) | ((uint)f2bf(v1) << 16);
            o.y = (uint)f2bf(v2) | ((uint)f2bf(v3) << 16);
            ((uint2*)outp)[(size_t)wid * 32 + lane] = o;
        } else {
            const int c = lane * 4;
            float p0 = v0 * Wout[c] + v1 * Wout[c + 1] + v2 * Wout[c + 2] + v3 * Wout[c + 3];
            float p1 = v0 * Wout[128 + c] + v1 * Wout[129 + c] + v2 * Wout[130 + c] +
                       v3 * Wout[131 + c];
#pragma unroll
            for (int off = 16; off > 0; off >>= 1) {
                p0 += __shfl_xor(p0, off);
                p1 += __shfl_xor(p1, off);
            }
            if (lane == 0) {
                ((float*)outp)[(size_t)wid * 2 + 0] = p0 + bout[0];
                ((float*)outp)[(size_t)wid * 2 + 1] = p1 + bout[1];
            }
        }
    }
}

extern "C" void kernel_launch(void* const* d_in, const int* in_sizes, int n_in,
                              void* d_out, int out_size, void* d_ws, size_t ws_size,
                              hipStream_t stream) {
    const float* x    = (const float*)d_in[0];
    const int*   ei   = (const int*)d_in[1];
    const float* Wl0  = (const float*)d_in[2];
    const float* bl0  = (const float*)d_in[3];
    const float* Wr0  = (const float*)d_in[4];
    const float* Wl1  = (const float*)d_in[5];
    const float* bl1  = (const float*)d_in[6];
    const float* Wr1  = (const float*)d_in[7];
    const float* Wl2  = (const float*)d_in[8];
    const float* bl2  = (const float*)d_in[9];
    const float* Wr2  = (const float*)d_in[10];
    const float* Wout = (const float*)d_in[11];
    const float* bout = (const float*)d_in[12];

    const int N = NN;
    const int E = in_sizes[1] / 2;
    const int* src = ei;
    const int* dst = ei + E;
    const int chunk = (E + NWG - 1) / NWG;

    // workspace carve-up (256B aligned)
    char* w = (char*)d_ws;
    auto alloc = [&](size_t bytes) {
        char* p = w;
        w += (bytes + 255) & ~(size_t)255;
        return p;
    };
    int*    cnt     = (int*)alloc((size_t)NWG * NBUCK * 4);
    int*    gaddr   = (int*)alloc((size_t)NWG * NBUCK * 4);
    int*    bdata   = (int*)alloc((size_t)E * 4);
    int*    row_off = (int*)alloc((size_t)(N + 1) * 4);
    float*  inv     = (float*)alloc((size_t)N * 4);
    int*    csr     = (int*)alloc((size_t)E * 4);
    ushort* Wl0h    = (ushort*)alloc((size_t)192 * HID * 2);
    ushort* Wr0h    = (ushort*)alloc((size_t)192 * HID * 2);
    ushort* Wl1h    = (ushort*)alloc((size_t)HID * HID * 2);
    ushort* Wr1h    = (ushort*)alloc((size_t)HID * HID * 2);
    ushort* Wl2h    = (ushort*)alloc((size_t)HID * HID * 2);
    ushort* Wr2h    = (ushort*)alloc((size_t)HID * HID * 2);
    ushort* B0      = (ushort*)alloc((size_t)N * HID * 2);   // bf16 messages (yl)
    ushort* B1      = (ushort*)alloc((size_t)N * HID * 2);   // bf16 yr / h
    ushort* B2      = (ushort*)alloc((size_t)N * HID * 2);   // bf16 yr / h

    // ---- CSR build (4-phase, no global atomics, coalesced stores) ----
    k_cnt<<<NWG, 256, 0, stream>>>(dst, E, chunk, cnt);
    k_cscan<<<1, 256, 0, stream>>>(cnt, gaddr);
    k_scatter<<<NWG, 256, 0, stream>>>(src, dst, E, chunk, gaddr, bdata);
    k_csr2<<<NBUCK, 256, 0, stream>>>(gaddr, bdata, E, csr, row_off, inv, N);

    // ---- weight packing ----
    k_wpack_all<<<(192 * HID + 255) / 256, 256, 0, stream>>>(
        Wl0, Wr0, Wl1, Wr1, Wl2, Wr2, Wl0h, Wr0h, Wl1h, Wr1h, Wl2h, Wr2h);

    const int gemm_grid = N / 32;   // 3125
    const int agg_grid = N / 4;     // 25000

    // ---- layer 0: h = x (fp32, K=165 pad 192) ----
    k_gemm_mfma<float, IN_CH, 192><<<gemm_grid, 256, 0, stream>>>(x, Wl0h, Wr0h, B0, B1);
    k_agg2<0><<<agg_grid, 256, 0, stream>>>(B0, row_off, csr, inv, bl0, B1, B1, nullptr, nullptr, N);

    // ---- layer 1 ----
    k_gemm_mfma<ushort, HID, HID><<<gemm_grid, 256, 0, stream>>>(B1, Wl1h, Wr1h, B0, B2);
    k_agg2<0><<<agg_grid, 256, 0, stream>>>(B0, row_off, csr, inv, bl1, B2, B2, nullptr, nullptr, N);

    // ---- layer 2 + fused output head ----
    k_gemm_mfma<ushort, HID, HID><<<gemm_grid, 256, 0, stream>>>(B2, Wl2h, Wr2h, B0, B1);
    k_agg2<1><<<agg_grid, 256, 0, stream>>>(B0, row_off, csr, inv, bl2, B1, d_out, Wout, bout, N);
}

// Round 8
// 371.122 us; speedup vs baseline: 2.3999x; 1.0377x over previous
//
#include <hip/hip_runtime.h>
#include <cstdint>
#include <cstddef>

#define NN 100000
#define IN_CH 165
#define HID 128

#define NBUCK 196     // ceil(100000/512) buckets of 512 nodes (dst>>9)
#define NPB 512
#define BMAX 10240    // max edges/bucket (mean 8163, +23 sigma)
#define NWG 256       // scatter/count workgroups

typedef __attribute__((ext_vector_type(8))) short short8;
typedef __attribute__((ext_vector_type(4))) float f32x4;

__device__ __forceinline__ ushort f2bf(float v) {
    uint b = __builtin_bit_cast(uint, v);
    return (ushort)((b + 0x7FFFu + ((b >> 16) & 1u)) >> 16);
}
__device__ __forceinline__ float bf2f(ushort u) {
    uint b = ((uint)u) << 16;
    return __builtin_bit_cast(float, b);
}
__device__ __forceinline__ float lo16f(uint u) { return __builtin_bit_cast(float, u << 16); }
__device__ __forceinline__ float hi16f(uint u) { return __builtin_bit_cast(float, u & 0xFFFF0000u); }

// ================= CSR build: 4-phase bucket sort, all stores coalesced =================
__global__ __launch_bounds__(256) void k_cnt(const int* __restrict__ dst, int E, int chunk,
                                             int* __restrict__ cnt) {
    __shared__ int h[NBUCK];
    const int w = blockIdx.x, t = threadIdx.x;
    for (int b = t; b < NBUCK; b += 256) h[b] = 0;
    __syncthreads();
    const int beg = w * chunk, end = min(E, beg + chunk);
    for (int i = beg + t; i < end; i += 256) atomicAdd(&h[dst[i] >> 9], 1);
    __syncthreads();
    for (int b = t; b < NBUCK; b += 256) cnt[w * NBUCK + b] = h[b];
}

// scan of the NWG x NBUCK count matrix in (b-major, w-minor) order; m = b*NWG + w
__global__ __launch_bounds__(256) void k_cscan(const int* __restrict__ cnt,
                                               int* __restrict__ gaddr) {
    __shared__ int ps[256];
    const int t = threadIdx.x;           // 50176 = 256 * 196
    int s = 0;
    for (int k = 0; k < NBUCK; k++) {
        const int m = t * NBUCK + k;
        s += cnt[(m & (NWG - 1)) * NBUCK + (m >> 8)];
    }
    ps[t] = s;
    __syncthreads();
    for (int off = 1; off < 256; off <<= 1) {
        int v = (t >= off) ? ps[t - off] : 0;
        __syncthreads();
        ps[t] += v;
        __syncthreads();
    }
    int run = (t > 0) ? ps[t - 1] : 0;
    for (int k = 0; k < NBUCK; k++) {
        const int m = t * NBUCK + k;
        gaddr[m] = run;
        run += cnt[(m & (NWG - 1)) * NBUCK + (m >> 8)];
    }
}

__global__ __launch_bounds__(256) void k_scatter(const int* __restrict__ src,
                                                 const int* __restrict__ dst, int E, int chunk,
                                                 const int* __restrict__ gaddr,
                                                 int* __restrict__ bdata) {
    __shared__ int cur[NBUCK];
    __shared__ int thist[256];
    __shared__ int sA[256];
    __shared__ int tex[NBUCK];
    __shared__ int lpos[NBUCK];
    __shared__ int staged[2048];
    __shared__ int addrs[2048];
    const int w = blockIdx.x, t = threadIdx.x;
    for (int b = t; b < NBUCK; b += 256) cur[b] = gaddr[b * NWG + w];
    const int beg = w * chunk, end = min(E, beg + chunk);
    for (int tb = beg; tb < end; tb += 2048) {
        const int tcnt = min(2048, end - tb);
        int key[8], bk[8];
#pragma unroll
        for (int j = 0; j < 8; j++) {
            const int i = tb + j * 256 + t;
            if (i < end) {
                const int d = dst[i];
                bk[j] = d >> 9;
                key[j] = (src[i] << 9) | (d & 511);
            } else bk[j] = -1;
        }
        __syncthreads();
        thist[t] = 0;
        __syncthreads();
#pragma unroll
        for (int j = 0; j < 8; j++)
            if (bk[j] >= 0) atomicAdd(&thist[bk[j]], 1);
        __syncthreads();
        sA[t] = thist[t];
        __syncthreads();
        for (int off = 1; off < 256; off <<= 1) {
            int v = (t >= off) ? sA[t - off] : 0;
            __syncthreads();
            sA[t] += v;
            __syncthreads();
        }
        if (t < NBUCK) {
            const int e = sA[t] - thist[t];
            tex[t] = e;
            lpos[t] = e;
        }
        __syncthreads();
#pragma unroll
        for (int j = 0; j < 8; j++)
            if (bk[j] >= 0) {
                const int b = bk[j];
                const int l = atomicAdd(&lpos[b], 1);
                staged[l] = key[j];
                addrs[l] = cur[b] + (l - tex[b]);
            }
        __syncthreads();
        for (int l = t; l < tcnt; l += 256) bdata[addrs[l]] = staged[l];
        __syncthreads();
        if (t < NBUCK) cur[t] += thist[t];
    }
}

__global__ __launch_bounds__(256) void k_csr2(const int* __restrict__ gaddr,
                                              const int* __restrict__ bdata, int E,
                                              int* __restrict__ csr, int* __restrict__ row_off,
                                              float* __restrict__ inv, int N) {
    __shared__ int keys[BMAX];
    __shared__ int sorted[BMAX];
    __shared__ int h5[NPB];
    __shared__ int s5[NPB];
    const int b = blockIdx.x, t = threadIdx.x;
    const int base = gaddr[b * NWG];
    const int nxt = (b == NBUCK - 1) ? E : gaddr[(b + 1) * NWG];
    const int tot = min(nxt - base, BMAX);
    for (int i = t; i < tot; i += 256) keys[i] = bdata[base + i];
    h5[t] = 0;
    h5[t + 256] = 0;
    __syncthreads();
    for (int i = t; i < tot; i += 256) atomicAdd(&h5[keys[i] & 511], 1);
    __syncthreads();
    s5[t] = h5[t];
    s5[t + 256] = h5[t + 256];
    __syncthreads();
    for (int off = 1; off < 512; off <<= 1) {
        const int a = (t >= off) ? s5[t - off] : 0;
        const int c = (t + 256 >= off) ? s5[t + 256 - off] : 0;
        __syncthreads();
        s5[t] += a;
        s5[t + 256] += c;
        __syncthreads();
    }
    const int e0 = s5[t] - h5[t];
    const int e1 = s5[t + 256] - h5[t + 256];
    __syncthreads();
    s5[t] = e0;
    s5[t + 256] = e1;
    const int n0 = b * NPB + t, n1 = b * NPB + t + 256;
    if (n0 < N) { row_off[n0] = base + e0; inv[n0] = 1.0f / (float)max(h5[t], 1); }
    if (n1 < N) { row_off[n1] = base + e1; inv[n1] = 1.0f / (float)max(h5[t + 256], 1); }
    if (b == 0 && t == 0) row_off[N] = E;
    __syncthreads();
    for (int i = t; i < tot; i += 256) {
        const int k = keys[i];
        const int p = atomicAdd(&s5[k & 511], 1);
        sorted[p] = k;
    }
    __syncthreads();
    for (int i = t; i < tot; i += 256) csr[base + i] = sorted[i] >> 9;
}

// ================= weight pack (bf16, k-blocked) =================
__device__ __forceinline__ void wpack_one(const float* __restrict__ W, int K, int idx,
                                          ushort* __restrict__ Wh) {
    const int k = idx >> 7;
    const int j = idx & 127;
    const float v = (k < K) ? W[j * K + k] : 0.0f;
    const int o = (k >> 3) * (HID * 8) + j * 8 + (k & 7);
    Wh[o] = f2bf(v);
}

__global__ void k_wpack_all(const float* __restrict__ Wl0, const float* __restrict__ Wr0,
                            const float* __restrict__ Wl1, const float* __restrict__ Wr1,
                            const float* __restrict__ Wl2, const float* __restrict__ Wr2,
                            ushort* __restrict__ Wl0h, ushort* __restrict__ Wr0h,
                            ushort* __restrict__ Wl1h, ushort* __restrict__ Wr1h,
                            ushort* __restrict__ Wl2h, ushort* __restrict__ Wr2h) {
    const int gid = blockIdx.x * blockDim.x + threadIdx.x;
    if (gid < 192 * HID) {
        wpack_one(Wl0, IN_CH, gid, Wl0h);
        wpack_one(Wr0, IN_CH, gid, Wr0h);
    }
    if (gid < 128 * HID) {
        wpack_one(Wl1, HID, gid, Wl1h);
        wpack_one(Wr1, HID, gid, Wr1h);
        wpack_one(Wl2, HID, gid, Wl2h);
        wpack_one(Wr2, HID, gid, Wr2h);
    }
}

// ================= MFMA dual GEMM (pure bf16); outputs yl, yr both bf16 =================
template <typename TIN, int K, int KP>
__global__ __launch_bounds__(256) void k_gemm_mfma(
    const TIN* __restrict__ h,
    const ushort* __restrict__ Wlh, const ushort* __restrict__ Wrh,
    ushort* __restrict__ yl, ushort* __restrict__ yr)
{
    constexpr int RS = KP * 2;  // LDS row stride (bytes)
    __shared__ __align__(16) char Ah[32 * RS];
    const int tid = threadIdx.x;
    const int node0 = blockIdx.x * 32;
    const TIN* __restrict__ hp = h + (size_t)node0 * K;

    if constexpr (sizeof(TIN) == 2) {
        constexpr int Q = 32 * (KP / 8);
        for (int q = tid; q < Q; q += 256) {
            const int r = q / (KP / 8);
            const int kp = (q - r * (KP / 8)) * 8;
            const short8 v = *reinterpret_cast<const short8*>(&hp[r * K + kp]);
            const int byte = r * RS + ((kp * 2) ^ ((r & 7) << 4));
            *reinterpret_cast<short8*>(Ah + byte) = v;
        }
    } else {
        constexpr int Q = 32 * (KP / 4);
        for (int q = tid; q < Q; q += 256) {
            const int r = q / (KP / 4);
            const int kp = (q - r * (KP / 4)) * 4;
            float v0, v1, v2, v3;
            if constexpr (K % 4 == 0) {
                const float4 v = *reinterpret_cast<const float4*>(&hp[r * K + kp]);
                v0 = v.x; v1 = v.y; v2 = v.z; v3 = v.w;
            } else {
                v0 = (kp + 0 < K) ? hp[r * K + kp + 0] : 0.0f;
                v1 = (kp + 1 < K) ? hp[r * K + kp + 1] : 0.0f;
                v2 = (kp + 2 < K) ? hp[r * K + kp + 2] : 0.0f;
                v3 = (kp + 3 < K) ? hp[r * K + kp + 3] : 0.0f;
            }
            const int byte = r * RS + ((kp * 2) ^ ((r & 7) << 4));
            *reinterpret_cast<ushort4*>(Ah + byte) =
                make_ushort4(f2bf(v0), f2bf(v1), f2bf(v2), f2bf(v3));
        }
    }
    __syncthreads();

    const int lane = tid & 63;
    const int w = tid >> 6;
    const int trow = lane & 15;
    const int kg = lane >> 4;
    const ushort* __restrict__ Bh = (w & 1) ? Wrh : Wlh;
    ushort* __restrict__ yo = (w & 1) ? yr : yl;
    const int cb0 = (w >> 1) * 4;

    f32x4 acc[2][4];
#pragma unroll
    for (int a = 0; a < 2; ++a)
#pragma unroll
        for (int b = 0; b < 4; ++b) acc[a][b] = (f32x4){0.f, 0.f, 0.f, 0.f};

    const int xo = (trow & 7) << 4;
    const char* __restrict__ pA0 = Ah + trow * RS;
    const char* __restrict__ pA1 = Ah + (trow + 16) * RS;

    constexpr int KS = KP / 32;
    for (int ks = 0; ks < KS; ++ks) {
        const int kbyte = (ks * 64 + kg * 16) ^ xo;
        const short8 a0h = *reinterpret_cast<const short8*>(pA0 + kbyte);
        const short8 a1h = *reinterpret_cast<const short8*>(pA1 + kbyte);
        const int bbase = (ks * 4 + kg) * (HID * 8) + trow * 8;
#pragma unroll
        for (int ci = 0; ci < 4; ++ci) {
            const short8 bh = *reinterpret_cast<const short8*>(Bh + bbase + (cb0 + ci) * 128);
            acc[0][ci] = __builtin_amdgcn_mfma_f32_16x16x32_bf16(a0h, bh, acc[0][ci], 0, 0, 0);
            acc[1][ci] = __builtin_amdgcn_mfma_f32_16x16x32_bf16(a1h, bh, acc[1][ci], 0, 0, 0);
        }
    }

#pragma unroll
    for (int rb = 0; rb < 2; ++rb) {
        const int nb_ = node0 + rb * 16 + kg * 4;
#pragma unroll
        for (int ci = 0; ci < 4; ++ci) {
            const int col = (cb0 + ci) * 16 + trow;
            const f32x4 a = acc[rb][ci];
#pragma unroll
            for (int rr = 0; rr < 4; ++rr)
                yo[(size_t)(nb_ + rr) * HID + col] = f2bf(a[rr]);
        }
    }
}

// ================= aggregate + combine; wave per node, 4 edges per load-instr =================
// lane = eslot*16 + c: edge-slot eslot (0..3) handles edges e+eslot, column group c
// covers channels 8c..8c+7 via one uint4 (16B, 8 bf16). Main loop: 16 edges, 4 loads
// in flight. Reduce across eslots with shfl_xor(16|32); epilogue on lanes 0..15.
template <int HEAD>
__global__ __launch_bounds__(256) void k_agg2(
    const ushort* __restrict__ yl, const int* __restrict__ row_off,
    const int* __restrict__ csr, const float* __restrict__ inv,
    const float* __restrict__ bias, const ushort* __restrict__ yr,
    void* __restrict__ outp, const float* __restrict__ Wout,
    const float* __restrict__ bout, int N)
{
    const int wid = (blockIdx.x * 256 + (int)threadIdx.x) >> 6;
    const int lane = threadIdx.x & 63;
    if (wid >= N) return;
    const int eslot = lane >> 4;
    const int c = lane & 15;
    const int beg = row_off[wid];
    const int end = row_off[wid + 1];
    const uint4* __restrict__ Y = (const uint4*)yl;   // 16 uint4 per row

    float a0 = 0.f, a1 = 0.f, a2 = 0.f, a3 = 0.f;
    float a4 = 0.f, a5 = 0.f, a6 = 0.f, a7 = 0.f;
    auto acc8 = [&](uint4 u) {
        a0 += lo16f(u.x); a1 += hi16f(u.x);
        a2 += lo16f(u.y); a3 += hi16f(u.y);
        a4 += lo16f(u.z); a5 += hi16f(u.z);
        a6 += lo16f(u.w); a7 += hi16f(u.w);
    };

    int e = beg;
    for (; e + 16 <= end; e += 16) {
        const int s0 = csr[e + eslot];
        const int s1 = csr[e + 4 + eslot];
        const int s2 = csr[e + 8 + eslot];
        const int s3 = csr[e + 12 + eslot];
        const uint4 u0 = Y[(size_t)s0 * 16 + c];
        const uint4 u1 = Y[(size_t)s1 * 16 + c];
        const uint4 u2 = Y[(size_t)s2 * 16 + c];
        const uint4 u3 = Y[(size_t)s3 * 16 + c];
        acc8(u0); acc8(u1); acc8(u2); acc8(u3);
    }
    if (e + 8 <= end) {
        const int s0 = csr[e + eslot];
        const int s1 = csr[e + 4 + eslot];
        const uint4 u0 = Y[(size_t)s0 * 16 + c];
        const uint4 u1 = Y[(size_t)s1 * 16 + c];
        acc8(u0); acc8(u1);
        e += 8;
    }
    if (e + 4 <= end) {
        const uint4 u0 = Y[(size_t)csr[e + eslot] * 16 + c];
        acc8(u0);
        e += 4;
    }
    if (e + eslot < end) {
        const uint4 u0 = Y[(size_t)csr[e + eslot] * 16 + c];
        acc8(u0);
    }

    a0 += __shfl_xor(a0, 16); a1 += __shfl_xor(a1, 16);
    a2 += __shfl_xor(a2, 16); a3 += __shfl_xor(a3, 16);
    a4 += __shfl_xor(a4, 16); a5 += __shfl_xor(a5, 16);
    a6 += __shfl_xor(a6, 16); a7 += __shfl_xor(a7, 16);
    a0 += __shfl_xor(a0, 32); a1 += __shfl_xor(a1, 32);
    a2 += __shfl_xor(a2, 32); a3 += __shfl_xor(a3, 32);
    a4 += __shfl_xor(a4, 32); a5 += __shfl_xor(a5, 32);
    a6 += __shfl_xor(a6, 32); a7 += __shfl_xor(a7, 32);

    if (lane < 16) {
        const float iv = inv[wid];
        const uint4 rv = ((const uint4*)yr)[(size_t)wid * 16 + lane];
        const float4 b0 = ((const float4*)bias)[lane * 2];
        const float4 b1 = ((const float4*)bias)[lane * 2 + 1];
        const float v0 = a0 * iv + b0.x + lo16f(rv.x);
        const float v1 = a1 * iv + b0.y + hi16f(rv.x);
        const float v2 = a2 * iv + b0.z + lo16f(rv.y);
        const float v3 = a3 * iv + b0.w + hi16f(rv.y);
        const float v4 = a4 * iv + b1.x + lo16f(rv.z);
        const float v5 = a5 * iv + b1.y + hi16f(rv.z);
        const float v6 = a6 * iv + b1.z + lo16f(rv.w);
        const float v7 = a7 * iv + b1.w + hi16f(rv.w);
        if constexpr (!HEAD) {
            uint4 o;
            o.x = (uint)f2bf(fmaxf(v0, 0.f)) | ((uint)f2bf(fmaxf(v1, 0.f)) << 16);
            o.y = (uint)f2bf(fmaxf(v2, 0.f)) | ((uint)f2bf(fmaxf(v3, 0.f)) << 16);
            o.z = (uint)f2bf(fmaxf(v4, 0.f)) | ((uint)f2bf(fmaxf(v5, 0.f)) << 16);
            o.w = (uint)f2bf(fmaxf(v6, 0.f)) | ((uint)f2bf(fmaxf(v7, 0.f)) << 16);
            ((uint4*)outp)[(size_t)wid * 16 + lane] = o;
        } else {
            const int ch = lane * 8;
            float p0 = v0 * Wout[ch + 0] + v1 * Wout[ch + 1] + v2 * Wout[ch + 2] +
                       v3 * Wout[ch + 3] + v4 * Wout[ch + 4] + v5 * Wout[ch + 5] +
                       v6 * Wout[ch + 6] + v7 * Wout[ch + 7];
            float p1 = v0 * Wout[128 + ch + 0] + v1 * Wout[128 + ch + 1] +
                       v2 * Wout[128 + ch + 2] + v3 * Wout[128 + ch + 3] +
                       v4 * Wout[128 + ch + 4] + v5 * Wout[128 + ch + 5] +
                       v6 * Wout[128 + ch + 6] + v7 * Wout[128 + ch + 7];
#pragma unroll
            for (int off = 8; off > 0; off >>= 1) {
                p0 += __shfl_xor(p0, off);
                p1 += __shfl_xor(p1, off);
            }
            if (lane == 0) {
                ((float*)outp)[(size_t)wid * 2 + 0] = p0 + bout[0];
                ((float*)outp)[(size_t)wid * 2 + 1] = p1 + bout[1];
            }
        }
    }
}

extern "C" void kernel_launch(void* const* d_in, const int* in_sizes, int n_in,
                              void* d_out, int out_size, void* d_ws, size_t ws_size,
                              hipStream_t stream) {
    const float* x    = (const float*)d_in[0];
    const int*   ei   = (const int*)d_in[1];
    const float* Wl0  = (const float*)d_in[2];
    const float* bl0  = (const float*)d_in[3];
    const float* Wr0  = (const float*)d_in[4];
    const float* Wl1  = (const float*)d_in[5];
    const float* bl1  = (const float*)d_in[6];
    const float* Wr1  = (const float*)d_in[7];
    const float* Wl2  = (const float*)d_in[8];
    const float* bl2  = (const float*)d_in[9];
    const float* Wr2  = (const float*)d_in[10];
    const float* Wout = (const float*)d_in[11];
    const float* bout = (const float*)d_in[12];

    const int N = NN;
    const int E = in_sizes[1] / 2;
    const int* src = ei;
    const int* dst = ei + E;
    const int chunk = (E + NWG - 1) / NWG;

    // workspace carve-up (256B aligned)
    char* w = (char*)d_ws;
    auto alloc = [&](size_t bytes) {
        char* p = w;
        w += (bytes + 255) & ~(size_t)255;
        return p;
    };
    int*    cnt     = (int*)alloc((size_t)NWG * NBUCK * 4);
    int*    gaddr   = (int*)alloc((size_t)NWG * NBUCK * 4);
    int*    bdata   = (int*)alloc((size_t)E * 4);
    int*    row_off = (int*)alloc((size_t)(N + 1) * 4);
    float*  inv     = (float*)alloc((size_t)N * 4);
    int*    csr     = (int*)alloc((size_t)E * 4);
    ushort* Wl0h    = (ushort*)alloc((size_t)192 * HID * 2);
    ushort* Wr0h    = (ushort*)alloc((size_t)192 * HID * 2);
    ushort* Wl1h    = (ushort*)alloc((size_t)HID * HID * 2);
    ushort* Wr1h    = (ushort*)alloc((size_t)HID * HID * 2);
    ushort* Wl2h    = (ushort*)alloc((size_t)HID * HID * 2);
    ushort* Wr2h    = (ushort*)alloc((size_t)HID * HID * 2);
    ushort* B0      = (ushort*)alloc((size_t)N * HID * 2);   // bf16 messages (yl)
    ushort* B1      = (ushort*)alloc((size_t)N * HID * 2);   // bf16 yr / h
    ushort* B2      = (ushort*)alloc((size_t)N * HID * 2);   // bf16 yr / h

    // ---- CSR build (4-phase, no global atomics, coalesced stores) ----
    k_cnt<<<NWG, 256, 0, stream>>>(dst, E, chunk, cnt);
    k_cscan<<<1, 256, 0, stream>>>(cnt, gaddr);
    k_scatter<<<NWG, 256, 0, stream>>>(src, dst, E, chunk, gaddr, bdata);
    k_csr2<<<NBUCK, 256, 0, stream>>>(gaddr, bdata, E, csr, row_off, inv, N);

    // ---- weight packing ----
    k_wpack_all<<<(192 * HID + 255) / 256, 256, 0, stream>>>(
        Wl0, Wr0, Wl1, Wr1, Wl2, Wr2, Wl0h, Wr0h, Wl1h, Wr1h, Wl2h, Wr2h);

    const int gemm_grid = N / 32;   // 3125
    const int agg_grid = N / 4;     // 25000

    // ---- layer 0: h = x (fp32, K=165 pad 192) ----
    k_gemm_mfma<float, IN_CH, 192><<<gemm_grid, 256, 0, stream>>>(x, Wl0h, Wr0h, B0, B1);
    k_agg2<0><<<agg_grid, 256, 0, stream>>>(B0, row_off, csr, inv, bl0, B1, B1, nullptr, nullptr, N);

    // ---- layer 1 ----
    k_gemm_mfma<ushort, HID, HID><<<gemm_grid, 256, 0, stream>>>(B1, Wl1h, Wr1h, B0, B2);
    k_agg2<0><<<agg_grid, 256, 0, stream>>>(B0, row_off, csr, inv, bl1, B2, B2, nullptr, nullptr, N);

    // ---- layer 2 + fused output head ----
    k_gemm_mfma<ushort, HID, HID><<<gemm_grid, 256, 0, stream>>>(B2, Wl2h, Wr2h, B0, B1);
    k_agg2<1><<<agg_grid, 256, 0, stream>>>(B0, row_off, csr, inv, bl2, B1, d_out, Wout, bout, N);
}